// Round 6
// baseline (603.752 us; speedup 1.0000x reference)
//
#include <hip/hip_runtime.h>
#include <hip/hip_bf16.h>

typedef __hip_bfloat16 bf16;
typedef __attribute__((ext_vector_type(8))) short bf16x8;
typedef __attribute__((ext_vector_type(4))) float f32x4;
typedef __attribute__((ext_vector_type(4))) unsigned short us4;
typedef __attribute__((ext_vector_type(8))) unsigned short us8;

// Problem constants
#define NB   256           // batch
#define NN   23            // nodes
#define NL   35            // seq len
#define NNL  805           // NN*NL
#define CNL  51520         // NC*NNL (per-batch x elements)
#define NSQ  529           // NN*NN
#define HF   1587          // NH*NSQ
#define NCN  1472          // 64*23 (one X_l slice)

// ws layout (float offsets)
#define OFF_W     0         // [3][64][64]
#define OFF_U1    12288
#define OFF_U2    12480
#define OFF_S     12672
#define OFF_ATTM  12800     // [256][1587]
#define OFF_MEAN  419072
#define OFF_RSTD  420672
#define OFF_A     422272    // [256][1587] -> 828544
#define OFF_MWH   828544    // mw bf16 hi [3][64o][64c] (12288 shorts)
#define OFF_MWL   834688    // mw bf16 lo
#define OFF_MBS   840832    // mbsum[64] -> pad 840960
#define OFF_XTB   840960    // X^T bf16 hi/lo [256][35][2 planes][23n][64c]

// split-bf16 helpers: x = hi + lo, each exactly representable in bf16
__device__ inline unsigned short bfh(float x) {
    unsigned u = __float_as_uint(x);
    return (unsigned short)((u + 0x7FFFu + ((u >> 16) & 1u)) >> 16);  // RNE
}
__device__ inline float bfh2f(unsigned short h) {
    return __uint_as_float(((unsigned)h) << 16);
}
// RNE f32->bf16 via HW cvt (numerically identical to bfh for finite inputs)
__device__ inline unsigned short bf16rn(float x) {
    __hip_bfloat16 h = __float2bfloat16(x);
    return __builtin_bit_cast(unsigned short, h);
}

// ---------------------------------------------------------------------------
// Kernel 0: transpose x[b][c][n][l] -> X^T bf16 hi/lo [b][l][p][n][c].
__global__ __launch_bounds__(1024) void k_xt(const float* __restrict__ x,
                                             float* __restrict__ ws) {
    int b = blockIdx.x, t = threadIdx.x;
    __shared__ float sx[64 * 23 * 18];   // 106 KB
    const float* xb = x + b * CNL;
    unsigned short* xo = (unsigned short*)(ws + OFF_XTB) + (size_t)b * NL * 2944;
    for (int lh = 0; lh < 2; lh++) {
        int l0 = lh * 18, Lc = lh ? 17 : 18;
        if (lh) __syncthreads();
        for (int i = t; i < 1472 * Lc; i += 1024) {
            int cn = i / Lc, li = i - cn * Lc;        // cn = c*23+n
            sx[cn * 18 + li] = xb[cn * 35 + l0 + li];
        }
        __syncthreads();
        for (int item = t; item < 184 * Lc; item += 1024) {
            int li = item / 184, rem = item - li * 184;
            int n = rem >> 3, k = rem & 7;
            us8 hi, lo;
            #pragma unroll
            for (int e = 0; e < 8; e++) {
                float v = sx[((8 * k + e) * 23 + n) * 18 + li];
                unsigned short hb = bfh(v);
                hi[e] = hb;
                lo[e] = bfh(v - bfh2f(hb));
            }
            unsigned short* dst = xo + (size_t)(l0 + li) * 2944 + n * 64 + 8 * k;
            *(us8*)(dst) = hi;           // plane hi
            *(us8*)(dst + 1472) = lo;    // plane lo
        }
    }
}

// ---------------------------------------------------------------------------
// Kernel 1: fold projection weights; block 3 converts mw to bf16 hi/lo + mb sum.
__global__ __launch_bounds__(256) void k_prep(const float* __restrict__ cw1,
                                              const float* __restrict__ cb1,
                                              const float* __restrict__ cw2,
                                              const float* __restrict__ cb2,
                                              const float* __restrict__ mw,
                                              const float* __restrict__ mb,
                                              float* __restrict__ ws) {
    int h = blockIdx.x, t = threadIdx.x;
    __shared__ float s1[4096], s2[4096];
    if (h < 3) {
        for (int i = t; i < 4096; i += 256) {
            s1[i] = cw1[h * 4096 + i];
            s2[i] = cw2[h * 4096 + i];
        }
        __syncthreads();
        for (int i = t; i < 4096; i += 256) {
            int c2 = i >> 6, c1 = i & 63;
            float acc = 0.f;
            for (int o = 0; o < 64; o++) acc += s2[o * 64 + c2] * s1[o * 64 + c1];
            ws[OFF_W + h * 4096 + i] = acc;
        }
        if (t < 64) {
            float a = 0.f, b2 = 0.f;
            for (int o = 0; o < 64; o++) {
                a  += cb2[h * 64 + o] * s1[o * 64 + t];
                b2 += cb1[h * 64 + o] * s2[o * 64 + t];
            }
            ws[OFF_U1 + h * 64 + t] = a;
            ws[OFF_U2 + h * 64 + t] = b2;
        }
        if (t == 0) {
            float a = 0.f;
            for (int o = 0; o < 64; o++) a += cb1[h * 64 + o] * cb2[h * 64 + o];
            ws[OFF_S + h] = a;
        }
    } else {
        unsigned short* mh = (unsigned short*)(ws + OFF_MWH);
        unsigned short* ml = (unsigned short*)(ws + OFF_MWL);
        for (int i = t; i < 12288; i += 256) {
            float v = mw[i];                 // layout [h][o][c]
            unsigned short hb = bfh(v);
            mh[i] = hb;
            ml[i] = bfh(v - bfh2f(hb));
        }
        if (t < 64) ws[OFF_MBS + t] = mb[t] + mb[64 + t] + mb[128 + t];
    }
}

// ---------------------------------------------------------------------------
// Kernel 2 (MFMA): att_m[b,h,m,n] = (sum_l X_l^T W X_l + a1[n] + a2[m] + 35*s)/2240
// T14: issue l+1 loads right after bar1; write idle buffer after phase A.
__global__ __launch_bounds__(256) void k_attm(float* __restrict__ ws) {
    const int b = blockIdx.x, h = blockIdx.y, t = threadIdx.x;
    const int lane = t & 63;
    const int w = __builtin_amdgcn_readfirstlane(t >> 6);   // wave 0..3
    const int lg = lane >> 4;      // k-group 0..3
    const int lr = lane & 15;      // row/col within 16-tile

    __shared__ unsigned short sXh[2][32 * 72];   // X^T hi, double-buffered
    __shared__ unsigned short sXl[2][32 * 72];   // X^T lo
    __shared__ unsigned short sPh[32 * 72];      // P^T hi  [n][c2]
    __shared__ unsigned short sPl[32 * 72];      // P^T lo
    __shared__ float sxs[64 * 25];               // sum_l X  [c][n], stride 25
    __shared__ float sA1[23], sA2[23];

    const unsigned short* xthl = (const unsigned short*)(ws + OFF_XTB);

    // --- W fragments (phase-A A-operand), hoisted: rows 16w+lr, split hi/lo ---
    bf16x8 wh[2], wl[2];
    {
        const float* Wg = ws + OFF_W + h * 4096 + (16 * w + lr) * 64;
        #pragma unroll
        for (int s = 0; s < 2; s++) {
            const float* p = Wg + 32 * s + 8 * lg;
            float4 v0 = *(const float4*)(p);
            float4 v1 = *(const float4*)(p + 4);
            float vv[8] = {v0.x, v0.y, v0.z, v0.w, v1.x, v1.y, v1.z, v1.w};
            #pragma unroll
            for (int e = 0; e < 8; e++) {
                unsigned short hb = bfh(vv[e]);
                wh[s][e] = (short)hb;
                wl[s][e] = (short)bfh(vv[e] - bfh2f(hb));
            }
        }
    }

    // --- staging chunk decomposition (368 = 2 planes x 23 rows x 8 chunks) ---
    const int j1 = t;                              // chunk 1 (all threads)
    const int p1 = j1 / 184, r1 = j1 - p1 * 184;
    const int n1 = r1 >> 3, k1 = r1 & 7;
    unsigned short* d1 = (p1 ? sXl[0] : sXh[0]) + n1 * 72 + 8 * k1;
    const int j2 = 256 + t;                        // chunk 2 (t<112, plane lo)
    const int r2 = j2 - 184;
    const int n2 = r2 >> 3, k2 = r2 & 7;
    unsigned short* d2 = sXl[0] + n2 * 72 + 8 * k2;

    const int mt = w >> 1, nt = w & 1;             // phase-B tile
    f32x4 attC = {0.f, 0.f, 0.f, 0.f};
    float xa1[8] = {0, 0, 0, 0, 0, 0, 0, 0};
    float xa2[8] = {0, 0, 0, 0, 0, 0, 0, 0};

    // --- prologue: stage l = 0 into buffer 0 ---
    {
        const us8* g = (const us8*)(xthl + (size_t)(b * NL) * 2944);
        us8 v1 = g[j1];
        *(us8*)(d1) = v1;
        #pragma unroll
        for (int e = 0; e < 8; e++) xa1[e] += bfh2f(v1[e]);
        if (t < 112) {
            us8 v2 = g[j2];
            *(us8*)(d2) = v2;
            #pragma unroll
            for (int e = 0; e < 8; e++) xa2[e] += bfh2f(v2[e]);
        }
    }

    #pragma unroll 1
    for (int l = 0; l < NL; l++) {
        const int cur = l & 1;
        __syncthreads();   // buf[cur] ready; prev-iter consumers done

        // issue next-l loads early (latency hides under phase A)
        us8 vn1, vn2;
        if (l < NL - 1) {
            const us8* g = (const us8*)(xthl + (size_t)(b * NL + l + 1) * 2944);
            vn1 = g[j1];
            if (t < 112) vn2 = g[j2];
        }

        const unsigned short* xh = sXh[cur];
        const unsigned short* xl = sXl[cur];

        // --- phase A: P rows [16w,16w+16) x n-tiles {0,1}, K = 64 ---
        f32x4 pc[2];
        #pragma unroll
        for (int ntt = 0; ntt < 2; ntt++) {
            f32x4 c = {0.f, 0.f, 0.f, 0.f};
            #pragma unroll
            for (int s = 0; s < 2; s++) {
                int off = (ntt * 16 + lr) * 72 + 32 * s + 8 * lg;
                bf16x8 bh = *(const bf16x8*)(xh + off);
                bf16x8 bl = *(const bf16x8*)(xl + off);
                c = __builtin_amdgcn_mfma_f32_16x16x32_bf16(wh[s], bh, c, 0, 0, 0);
                c = __builtin_amdgcn_mfma_f32_16x16x32_bf16(wh[s], bl, c, 0, 0, 0);
                c = __builtin_amdgcn_mfma_f32_16x16x32_bf16(wl[s], bh, c, 0, 0, 0);
            }
            pc[ntt] = c;
        }
        #pragma unroll
        for (int ntt = 0; ntt < 2; ntt++) {
            int n = ntt * 16 + lr;
            int c2 = 16 * w + 4 * lg;
            us4 ph4, pl4;
            #pragma unroll
            for (int r = 0; r < 4; r++) {
                float v = pc[ntt][r];
                unsigned short hb = bf16rn(v);
                ph4[r] = hb;
                pl4[r] = bf16rn(v - bfh2f(hb));
            }
            *(us4*)(sPh + n * 72 + c2) = ph4;
            *(us4*)(sPl + n * 72 + c2) = pl4;
        }

        // write-late: store next-l X into the idle buffer
        if (l < NL - 1) {
            *(us8*)(d1 + (cur ^ 1) * 2304) = vn1;
            #pragma unroll
            for (int e = 0; e < 8; e++) xa1[e] += bfh2f(vn1[e]);
            if (t < 112) {
                *(us8*)(d2 + (cur ^ 1) * 2304) = vn2;
                #pragma unroll
                for (int e = 0; e < 8; e++) xa2[e] += bfh2f(vn2[e]);
            }
        }
        __syncthreads();   // P ready

        // --- phase B: att(mt,nt) += X^T @ P, K = 64 ---
        #pragma unroll
        for (int s = 0; s < 2; s++) {
            int aoff = (mt * 16 + lr) * 72 + 32 * s + 8 * lg;
            int boff = (nt * 16 + lr) * 72 + 32 * s + 8 * lg;
            bf16x8 ah = *(const bf16x8*)(xh + aoff);
            bf16x8 al = *(const bf16x8*)(xl + aoff);
            bf16x8 bh = *(const bf16x8*)(sPh + boff);
            bf16x8 bl = *(const bf16x8*)(sPl + boff);
            attC = __builtin_amdgcn_mfma_f32_16x16x32_bf16(ah, bh, attC, 0, 0, 0);
            attC = __builtin_amdgcn_mfma_f32_16x16x32_bf16(ah, bl, attC, 0, 0, 0);
            attC = __builtin_amdgcn_mfma_f32_16x16x32_bf16(al, bh, attC, 0, 0, 0);
        }
    }

    // --- rank-1 correction terms from hi+lo column sums ---
    if (t < 184) {
        #pragma unroll
        for (int e = 0; e < 8; e++) sxs[(8 * k1 + e) * 25 + n1] = xa1[e];
    }
    __syncthreads();
    if (t >= 184) {
        #pragma unroll
        for (int e = 0; e < 8; e++) sxs[(8 * k1 + e) * 25 + n1] += xa1[e];
    }
    if (t < 112) {
        #pragma unroll
        for (int e = 0; e < 8; e++) sxs[(8 * k2 + e) * 25 + n2] += xa2[e];
    }
    __syncthreads();
    if (t < 23) {
        float a = 0.f;
        const float* u = ws + OFF_U1 + h * 64;
        for (int c = 0; c < 64; c++) a += u[c] * sxs[c * 25 + t];
        sA1[t] = a;
    } else if (t >= 32 && t < 55) {
        int n = t - 32;
        float a = 0.f;
        const float* u = ws + OFF_U2 + h * 64;
        for (int c = 0; c < 64; c++) a += u[c] * sxs[c * 25 + n];
        sA2[n] = a;
    }
    __syncthreads();

    float sh = ws[OFF_S + h];
    float* o = ws + OFF_ATTM + (size_t)b * HF + h * NSQ;
    int n = nt * 16 + lr;
    if (n < 23) {
        #pragma unroll
        for (int r = 0; r < 4; r++) {
            int m = mt * 16 + 4 * lg + r;
            if (m < 23)
                o[m * 23 + n] = (attC[r] + sA1[n] + sA2[m] + 35.f * sh) * (1.f / 2240.f);
        }
    }
}

// ---------------------------------------------------------------------------
// Kernel 3: BN batch statistics; 25 blocks x (64 features x 8 batch-groups).
__global__ __launch_bounds__(512) void k_bn(float* __restrict__ ws) {
    int t = threadIdx.x;
    int fi = t & 63, bg = t >> 6;
    int f = blockIdx.x * 64 + fi;
    __shared__ float rs[8][64], rs2[8][64];
    float s = 0.f, s2 = 0.f;
    if (f < HF) {
        const float* p = ws + OFF_ATTM + f + (size_t)bg * 32 * HF;
        for (int b = 0; b < 32; b++) {
            float v = p[b * HF];
            s += v; s2 += v * v;
        }
    }
    rs[bg][fi] = s; rs2[bg][fi] = s2;
    __syncthreads();
    if (bg == 0 && f < HF) {
        float ts = 0.f, ts2 = 0.f;
        #pragma unroll
        for (int g = 0; g < 8; g++) { ts += rs[g][fi]; ts2 += rs2[g][fi]; }
        float mean = ts * (1.f / 256.f);
        float var  = ts2 * (1.f / 256.f) - mean * mean;
        ws[OFF_MEAN + f] = mean;
        ws[OFF_RSTD + f] = rsqrtf(var + 1e-5f);
    }
}

// ---------------------------------------------------------------------------
// Kernel 4: normalize, softmax over rows, A = A_ske + att + A_adp.
__global__ __launch_bounds__(256) void k_adp(const float* __restrict__ gamma,
                                             const float* __restrict__ beta,
                                             const float* __restrict__ att,
                                             const float* __restrict__ aske,
                                             float* __restrict__ ws) {
    int b = blockIdx.x, h = blockIdx.y, t = threadIdx.x;
    __shared__ float sv[529];
    const float* am   = ws + OFF_ATTM + b * HF + h * NSQ;
    const float* mean = ws + OFF_MEAN + h * NSQ;
    const float* rstd = ws + OFF_RSTD + h * NSQ;
    for (int i = t; i < 529; i += 256) {
        sv[i] = (am[i] - mean[i]) * rstd[i] * gamma[h * NSQ + i] + beta[h * NSQ + i];
    }
    __syncthreads();
    if (t < 23) {
        float mx = -1e30f;
        #pragma unroll
        for (int m = 0; m < 23; m++) mx = fmaxf(mx, sv[m * 23 + t]);
        float e[23];
        float sum = 0.f;
        #pragma unroll
        for (int m = 0; m < 23; m++) {
            float v = __expf(sv[m * 23 + t] - mx);
            e[m] = v; sum += v;
        }
        float inv = 1.f / sum;
        #pragma unroll
        for (int m = 0; m < 23; m++) sv[m * 23 + t] = e[m] * inv;
    }
    __syncthreads();
    float* o = ws + OFF_A + b * HF + h * NSQ;
    for (int i = t; i < 529; i += 256) {
        o[i] = sv[i] + aske[h * NSQ + i] + att[h * NSQ + i];
    }
}

// ---------------------------------------------------------------------------
// Kernel 5 (fused GCN + temporal FC), one block per batch b, 8 waves.
// Y = sum_h (MW[h] @ X) @ A[h]. T14 staging; sT stride 44.
// FC accumulated IN REGISTERS: acc[4][35] fp32 per lane (no sY, no y rounding).
// W[l][*] via lane-uniform s_load from global. Epilogue: 4 r-chunks transpose
// acc through LDS for 805-float-contiguous coalesced out writes.
#define STS 44
__global__ __launch_bounds__(512, 2) void k_fused(float* __restrict__ ws,
                                                  const float* __restrict__ wseq,
                                                  const float* __restrict__ biasp,
                                                  float* __restrict__ out) {
    const int b = blockIdx.x, t = threadIdx.x;
    const int lane = t & 63;
    const int w = __builtin_amdgcn_readfirstlane(t >> 6);   // 0..7
    const int lg = lane >> 4, lr = lane & 15;
    const int nt = w >> 2, ot = w & 3;     // phase A' tile (n-tile, o-tile)
    const int ot2 = w >> 1, mt = w & 1;    // phase B' tile (o-tile, m-tile)

    __shared__ __align__(16) unsigned short sXh[32 * 72], sXl[32 * 72];
    __shared__ __align__(16) unsigned short sAT[3][2][32 * 40];  // A^T [m][n] hi/lo
    __shared__ __align__(16) unsigned short sT[3][64 * STS];     // T [o][n] hi only
    __shared__ __align__(16) float sEp[16 * 23 * 36];            // epilogue [oi][m][lp pad36]

    const unsigned short* xthl = (const unsigned short*)(ws + OFF_XTB);
    const float* Ab  = ws + OFF_A + (size_t)b * HF;

    // ---- one-time: zero sX rows 23..31 (they feed phase B's K-dim via T) ----
    for (int i = t; i < 9 * 72; i += 512) {
        sXh[23 * 72 + i] = 0;
        sXl[23 * 72 + i] = 0;
    }
    // ---- one-time staging (first in-loop barrier fences all of it) ----
    for (int i = t; i < 3 * 1280; i += 512) {
        int h = i / 1280, r2 = i - h * 1280, m = r2 / 40, n = r2 - m * 40;
        float v = (n < 23 && m < 23) ? Ab[h * 529 + n * 23 + m] : 0.f;
        unsigned short hb = bfh(v);
        sAT[h][0][m * 40 + n] = hb;
        sAT[h][1][m * 40 + n] = bfh(v - bfh2f(hb));
    }

    // ---- MW fragments as phase-A' B-operand (MW^T cols o = MW rows o) ----
    const unsigned short* mwh = (const unsigned short*)(ws + OFF_MWH);
    const unsigned short* mwl = (const unsigned short*)(ws + OFF_MWL);
    bf16x8 fwh[3][2], fwl[3][2];
    #pragma unroll
    for (int h = 0; h < 3; h++)
        #pragma unroll
        for (int s = 0; s < 2; s++) {
            int off = h * 4096 + (16 * ot + lr) * 64 + 32 * s + 8 * lg;
            fwh[h][s] = *(const bf16x8*)(mwh + off);
            fwl[h][s] = *(const bf16x8*)(mwl + off);
        }
    float4 mbsv = *(const float4*)(ws + OFF_MBS + 16 * ot2 + 4 * lg);
    float mb4[4] = {mbsv.x, mbsv.y, mbsv.z, mbsv.w};

    // staging chunk decomposition (t < 368 active)
    const int p1 = t / 184, r1 = t - p1 * 184;
    const int n1 = r1 >> 3, k1 = r1 & 7;
    unsigned short* d1 = (p1 ? sXl : sXh) + n1 * 72 + 8 * k1;

    const f32x4 zf = {0.f, 0.f, 0.f, 0.f};

    // FC accumulators (fp32, static-indexed only)
    float acc[4][35];
    #pragma unroll
    for (int r = 0; r < 4; r++)
        #pragma unroll
        for (int lp = 0; lp < 35; lp++) acc[r][lp] = 0.f;

    // prologue: stage l = 0
    if (t < 368) {
        const us8* g = (const us8*)(xthl + (size_t)(b * NL) * 2944);
        *(us8*)d1 = g[t];
    }

    #pragma unroll 1
    for (int l = 0; l < NL; l++) {
        __syncthreads();   // sX(l) ready

        // issue next-l load early (reg-carry; written after bar2)
        us8 vn;
        if (l < NL - 1 && t < 368) {
            const us8* g = (const us8*)(xthl + (size_t)(b * NL + l + 1) * 2944);
            vn = g[t];
        }

        // ---- phase A': T^T = X^T @ MW^T per h; M=n, N=o, K=c=64 ----
        bf16x8 xh0 = *(const bf16x8*)(sXh + (16 * nt + lr) * 72 + 8 * lg);
        bf16x8 xh1 = *(const bf16x8*)(sXh + (16 * nt + lr) * 72 + 32 + 8 * lg);
        bf16x8 xl0 = *(const bf16x8*)(sXl + (16 * nt + lr) * 72 + 8 * lg);
        bf16x8 xl1 = *(const bf16x8*)(sXl + (16 * nt + lr) * 72 + 32 + 8 * lg);
        #pragma unroll
        for (int h = 0; h < 3; h++) {
            f32x4 cH = __builtin_amdgcn_mfma_f32_16x16x32_bf16(xh0, fwh[h][0], zf, 0, 0, 0);
            cH = __builtin_amdgcn_mfma_f32_16x16x32_bf16(xh1, fwh[h][1], cH, 0, 0, 0);
            f32x4 cC = __builtin_amdgcn_mfma_f32_16x16x32_bf16(xh0, fwl[h][0], zf, 0, 0, 0);
            cC = __builtin_amdgcn_mfma_f32_16x16x32_bf16(xh1, fwl[h][1], cC, 0, 0, 0);
            cC = __builtin_amdgcn_mfma_f32_16x16x32_bf16(xl0, fwh[h][0], cC, 0, 0, 0);
            cC = __builtin_amdgcn_mfma_f32_16x16x32_bf16(xl1, fwh[h][1], cC, 0, 0, 0);
            us4 t4;
            #pragma unroll
            for (int r = 0; r < 4; r++) t4[r] = bf16rn(cH[r] + cC[r]);
            *(us4*)(&sT[h][(16 * ot + lr) * STS + 16 * nt + 4 * lg]) = t4;
        }
        __syncthreads();   // T ready; all phase-A' sX reads done

        // ---- phase B': Y(ot2,mt) = sum_h T[h] @ A[h]; K = n = 32 ----
        f32x4 Yh = zf, Yc = zf;
        #pragma unroll
        for (int h = 0; h < 3; h++) {
            union { bf16x8 v; us4 q[2]; } tu;
            tu.q[0] = *(const us4*)(&sT[h][(16 * ot2 + lr) * STS + 8 * lg]);
            tu.q[1] = *(const us4*)(&sT[h][(16 * ot2 + lr) * STS + 8 * lg + 4]);
            bf16x8 ah = *(const bf16x8*)(&sAT[h][0][(16 * mt + lr) * 40 + 8 * lg]);
            bf16x8 al = *(const bf16x8*)(&sAT[h][1][(16 * mt + lr) * 40 + 8 * lg]);
            Yh = __builtin_amdgcn_mfma_f32_16x16x32_bf16(tu.v, ah, Yh, 0, 0, 0);
            Yc = __builtin_amdgcn_mfma_f32_16x16x32_bf16(tu.v, al, Yc, 0, 0, 0);
        }

        // ---- FC accumulate in registers: acc[r][lp] += y_r * W[l][lp] ----
        float yv0 = Yh[0] + Yc[0] + mb4[0];
        float yv1 = Yh[1] + Yc[1] + mb4[1];
        float yv2 = Yh[2] + Yc[2] + mb4[2];
        float yv3 = Yh[3] + Yc[3] + mb4[3];
        const float* wr = wseq + l * 35;   // lane-uniform -> scalar loads
        #pragma unroll
        for (int lp = 0; lp < 35; lp++) {
            float wv = wr[lp];
            acc[0][lp] += yv0 * wv;
            acc[1][lp] += yv1 * wv;
            acc[2][lp] += yv2 * wv;
            acc[3][lp] += yv3 * wv;
        }

        // write-late: store next-l X (safe: bar2 proved all A' readers done)
        if (l < NL - 1 && t < 368) *(us8*)d1 = vn;
    }

    // ---- epilogue: 4 r-chunks through LDS, coalesced out writes ----
    const int oi = 4 * ot2 + lg;       // o = 4*oi + r
    const int m  = 16 * mt + lr;
    #pragma unroll 1
    for (int r = 0; r < 4; r++) {
        __syncthreads();               // sEp free (first iter: after last B')
        if (m < 23) {
            float* ep = sEp + (oi * 23 + m) * 36;
            #pragma unroll
            for (int lp = 0; lp < 35; lp++) ep[lp] = acc[r][lp] + biasp[lp];
        }
        __syncthreads();               // chunk ready
        for (int i = t; i < 16 * 805; i += 512) {
            int o16 = i / 805, rem = i - o16 * 805;   // rem = m*35+lp
            int mm = rem / 35, lp = rem - mm * 35;
            out[((size_t)(b * 1472 + (4 * o16 + r) * 23)) * 35 + rem] =
                sEp[(o16 * 23 + mm) * 36 + lp];
        }
    }
}

// ---------------------------------------------------------------------------
extern "C" void kernel_launch(void* const* d_in, const int* in_sizes, int n_in,
                              void* d_out, int out_size, void* d_ws, size_t ws_size,
                              hipStream_t stream) {
    const float* x    = (const float*)d_in[0];
    const float* cw1  = (const float*)d_in[1];
    const float* cb1  = (const float*)d_in[2];
    const float* cw2  = (const float*)d_in[3];
    const float* cb2  = (const float*)d_in[4];
    const float* gam  = (const float*)d_in[5];
    const float* bet  = (const float*)d_in[6];
    const float* mw   = (const float*)d_in[7];
    const float* mb   = (const float*)d_in[8];
    const float* att  = (const float*)d_in[9];
    const float* aske = (const float*)d_in[10];
    const float* wsq  = (const float*)d_in[11];
    const float* bias = (const float*)d_in[12];
    float* ws = (float*)d_ws;
    float* out = (float*)d_out;

    hipLaunchKernelGGL(k_prep, dim3(4),       dim3(256),  0, stream, cw1, cb1, cw2, cb2, mw, mb, ws);
    hipLaunchKernelGGL(k_xt,   dim3(256),     dim3(1024), 0, stream, x, ws);
    hipLaunchKernelGGL(k_attm, dim3(256, 3),  dim3(256),  0, stream, ws);
    hipLaunchKernelGGL(k_bn,   dim3(25),      dim3(512),  0, stream, ws);
    hipLaunchKernelGGL(k_adp,  dim3(256, 3),  dim3(256),  0, stream, gam, bet, att, aske, ws);
    hipLaunchKernelGGL(k_fused, dim3(256),    dim3(512),  0, stream, ws, wsq, bias, out);
}

// Round 7
// 267.682 us; speedup vs baseline: 2.2555x; 2.2555x over previous
//
#include <hip/hip_runtime.h>
#include <hip/hip_bf16.h>

typedef __hip_bfloat16 bf16;
typedef __attribute__((ext_vector_type(8))) short bf16x8;
typedef __attribute__((ext_vector_type(4))) float f32x4;
typedef __attribute__((ext_vector_type(4))) unsigned short us4;
typedef __attribute__((ext_vector_type(8))) unsigned short us8;

// Problem constants
#define NB   256           // batch
#define NN   23            // nodes
#define NL   35            // seq len
#define NNL  805           // NN*NL
#define CNL  51520         // NC*NNL (per-batch x elements)
#define NSQ  529           // NN*NN
#define HF   1587          // NH*NSQ
#define NCN  1472          // 64*23 (one X_l slice)

// ws layout (float offsets)
#define OFF_W     0         // [3][64][64]
#define OFF_U1    12288
#define OFF_U2    12480
#define OFF_S     12672
#define OFF_ATTM  12800     // [256][1587]
#define OFF_MEAN  419072
#define OFF_RSTD  420672
#define OFF_A     422272    // [256][1587] -> 828544
#define OFF_MWH   828544    // mw bf16 hi [3][64o][64c] (12288 shorts)
#define OFF_MWL   834688    // mw bf16 lo
#define OFF_MBS   840832    // mbsum[64] -> pad 840960
#define OFF_XTB   840960    // X^T bf16 hi/lo [256][35][2 planes][23n][64c]

// split-bf16 helpers: x = hi + lo, each exactly representable in bf16
__device__ inline unsigned short bfh(float x) {
    unsigned u = __float_as_uint(x);
    return (unsigned short)((u + 0x7FFFu + ((u >> 16) & 1u)) >> 16);  // RNE
}
__device__ inline float bfh2f(unsigned short h) {
    return __uint_as_float(((unsigned)h) << 16);
}
// RNE f32->bf16 via HW cvt (numerically identical to bfh for finite inputs)
__device__ inline unsigned short bf16rn(float x) {
    __hip_bfloat16 h = __float2bfloat16(x);
    return __builtin_bit_cast(unsigned short, h);
}

// ---------------------------------------------------------------------------
// Kernel 0: transpose x[b][c][n][l] -> X^T bf16 hi/lo [b][l][p][n][c].
__global__ __launch_bounds__(1024) void k_xt(const float* __restrict__ x,
                                             float* __restrict__ ws) {
    int b = blockIdx.x, t = threadIdx.x;
    __shared__ float sx[64 * 23 * 18];   // 106 KB
    const float* xb = x + b * CNL;
    unsigned short* xo = (unsigned short*)(ws + OFF_XTB) + (size_t)b * NL * 2944;
    for (int lh = 0; lh < 2; lh++) {
        int l0 = lh * 18, Lc = lh ? 17 : 18;
        if (lh) __syncthreads();
        for (int i = t; i < 1472 * Lc; i += 1024) {
            int cn = i / Lc, li = i - cn * Lc;        // cn = c*23+n
            sx[cn * 18 + li] = xb[cn * 35 + l0 + li];
        }
        __syncthreads();
        for (int item = t; item < 184 * Lc; item += 1024) {
            int li = item / 184, rem = item - li * 184;
            int n = rem >> 3, k = rem & 7;
            us8 hi, lo;
            #pragma unroll
            for (int e = 0; e < 8; e++) {
                float v = sx[((8 * k + e) * 23 + n) * 18 + li];
                unsigned short hb = bfh(v);
                hi[e] = hb;
                lo[e] = bfh(v - bfh2f(hb));
            }
            unsigned short* dst = xo + (size_t)(l0 + li) * 2944 + n * 64 + 8 * k;
            *(us8*)(dst) = hi;           // plane hi
            *(us8*)(dst + 1472) = lo;    // plane lo
        }
    }
}

// ---------------------------------------------------------------------------
// Kernel 1: fold projection weights; block 3 converts mw to bf16 hi/lo + mb sum.
__global__ __launch_bounds__(256) void k_prep(const float* __restrict__ cw1,
                                              const float* __restrict__ cb1,
                                              const float* __restrict__ cw2,
                                              const float* __restrict__ cb2,
                                              const float* __restrict__ mw,
                                              const float* __restrict__ mb,
                                              float* __restrict__ ws) {
    int h = blockIdx.x, t = threadIdx.x;
    __shared__ float s1[4096], s2[4096];
    if (h < 3) {
        for (int i = t; i < 4096; i += 256) {
            s1[i] = cw1[h * 4096 + i];
            s2[i] = cw2[h * 4096 + i];
        }
        __syncthreads();
        for (int i = t; i < 4096; i += 256) {
            int c2 = i >> 6, c1 = i & 63;
            float acc = 0.f;
            for (int o = 0; o < 64; o++) acc += s2[o * 64 + c2] * s1[o * 64 + c1];
            ws[OFF_W + h * 4096 + i] = acc;
        }
        if (t < 64) {
            float a = 0.f, b2 = 0.f;
            for (int o = 0; o < 64; o++) {
                a  += cb2[h * 64 + o] * s1[o * 64 + t];
                b2 += cb1[h * 64 + o] * s2[o * 64 + t];
            }
            ws[OFF_U1 + h * 64 + t] = a;
            ws[OFF_U2 + h * 64 + t] = b2;
        }
        if (t == 0) {
            float a = 0.f;
            for (int o = 0; o < 64; o++) a += cb1[h * 64 + o] * cb2[h * 64 + o];
            ws[OFF_S + h] = a;
        }
    } else {
        unsigned short* mh = (unsigned short*)(ws + OFF_MWH);
        unsigned short* ml = (unsigned short*)(ws + OFF_MWL);
        for (int i = t; i < 12288; i += 256) {
            float v = mw[i];                 // layout [h][o][c]
            unsigned short hb = bfh(v);
            mh[i] = hb;
            ml[i] = bfh(v - bfh2f(hb));
        }
        if (t < 64) ws[OFF_MBS + t] = mb[t] + mb[64 + t] + mb[128 + t];
    }
}

// ---------------------------------------------------------------------------
// Kernel 2 (MFMA): att_m[b,h,m,n] = (sum_l X_l^T W X_l + a1[n] + a2[m] + 35*s)/2240
// T14: issue l+1 loads right after bar1; write idle buffer after phase A.
__global__ __launch_bounds__(256) void k_attm(float* __restrict__ ws) {
    const int b = blockIdx.x, h = blockIdx.y, t = threadIdx.x;
    const int lane = t & 63;
    const int w = __builtin_amdgcn_readfirstlane(t >> 6);   // wave 0..3
    const int lg = lane >> 4;      // k-group 0..3
    const int lr = lane & 15;      // row/col within 16-tile

    __shared__ unsigned short sXh[2][32 * 72];   // X^T hi, double-buffered
    __shared__ unsigned short sXl[2][32 * 72];   // X^T lo
    __shared__ unsigned short sPh[32 * 72];      // P^T hi  [n][c2]
    __shared__ unsigned short sPl[32 * 72];      // P^T lo
    __shared__ float sxs[64 * 25];               // sum_l X  [c][n], stride 25
    __shared__ float sA1[23], sA2[23];

    const unsigned short* xthl = (const unsigned short*)(ws + OFF_XTB);

    // --- W fragments (phase-A A-operand), hoisted: rows 16w+lr, split hi/lo ---
    bf16x8 wh[2], wl[2];
    {
        const float* Wg = ws + OFF_W + h * 4096 + (16 * w + lr) * 64;
        #pragma unroll
        for (int s = 0; s < 2; s++) {
            const float* p = Wg + 32 * s + 8 * lg;
            float4 v0 = *(const float4*)(p);
            float4 v1 = *(const float4*)(p + 4);
            float vv[8] = {v0.x, v0.y, v0.z, v0.w, v1.x, v1.y, v1.z, v1.w};
            #pragma unroll
            for (int e = 0; e < 8; e++) {
                unsigned short hb = bfh(vv[e]);
                wh[s][e] = (short)hb;
                wl[s][e] = (short)bfh(vv[e] - bfh2f(hb));
            }
        }
    }

    // --- staging chunk decomposition (368 = 2 planes x 23 rows x 8 chunks) ---
    const int j1 = t;                              // chunk 1 (all threads)
    const int p1 = j1 / 184, r1 = j1 - p1 * 184;
    const int n1 = r1 >> 3, k1 = r1 & 7;
    unsigned short* d1 = (p1 ? sXl[0] : sXh[0]) + n1 * 72 + 8 * k1;
    const int j2 = 256 + t;                        // chunk 2 (t<112, plane lo)
    const int r2 = j2 - 184;
    const int n2 = r2 >> 3, k2 = r2 & 7;
    unsigned short* d2 = sXl[0] + n2 * 72 + 8 * k2;

    const int mt = w >> 1, nt = w & 1;             // phase-B tile
    f32x4 attC = {0.f, 0.f, 0.f, 0.f};
    float xa1[8] = {0, 0, 0, 0, 0, 0, 0, 0};
    float xa2[8] = {0, 0, 0, 0, 0, 0, 0, 0};

    // --- prologue: stage l = 0 into buffer 0 ---
    {
        const us8* g = (const us8*)(xthl + (size_t)(b * NL) * 2944);
        us8 v1 = g[j1];
        *(us8*)(d1) = v1;
        #pragma unroll
        for (int e = 0; e < 8; e++) xa1[e] += bfh2f(v1[e]);
        if (t < 112) {
            us8 v2 = g[j2];
            *(us8*)(d2) = v2;
            #pragma unroll
            for (int e = 0; e < 8; e++) xa2[e] += bfh2f(v2[e]);
        }
    }

    #pragma unroll 1
    for (int l = 0; l < NL; l++) {
        const int cur = l & 1;
        __syncthreads();   // buf[cur] ready; prev-iter consumers done

        // issue next-l loads early (latency hides under phase A)
        us8 vn1, vn2;
        if (l < NL - 1) {
            const us8* g = (const us8*)(xthl + (size_t)(b * NL + l + 1) * 2944);
            vn1 = g[j1];
            if (t < 112) vn2 = g[j2];
        }

        const unsigned short* xh = sXh[cur];
        const unsigned short* xl = sXl[cur];

        // --- phase A: P rows [16w,16w+16) x n-tiles {0,1}, K = 64 ---
        f32x4 pc[2];
        #pragma unroll
        for (int ntt = 0; ntt < 2; ntt++) {
            f32x4 c = {0.f, 0.f, 0.f, 0.f};
            #pragma unroll
            for (int s = 0; s < 2; s++) {
                int off = (ntt * 16 + lr) * 72 + 32 * s + 8 * lg;
                bf16x8 bh = *(const bf16x8*)(xh + off);
                bf16x8 bl = *(const bf16x8*)(xl + off);
                c = __builtin_amdgcn_mfma_f32_16x16x32_bf16(wh[s], bh, c, 0, 0, 0);
                c = __builtin_amdgcn_mfma_f32_16x16x32_bf16(wh[s], bl, c, 0, 0, 0);
                c = __builtin_amdgcn_mfma_f32_16x16x32_bf16(wl[s], bh, c, 0, 0, 0);
            }
            pc[ntt] = c;
        }
        #pragma unroll
        for (int ntt = 0; ntt < 2; ntt++) {
            int n = ntt * 16 + lr;
            int c2 = 16 * w + 4 * lg;
            us4 ph4, pl4;
            #pragma unroll
            for (int r = 0; r < 4; r++) {
                float v = pc[ntt][r];
                unsigned short hb = bf16rn(v);
                ph4[r] = hb;
                pl4[r] = bf16rn(v - bfh2f(hb));
            }
            *(us4*)(sPh + n * 72 + c2) = ph4;
            *(us4*)(sPl + n * 72 + c2) = pl4;
        }

        // write-late: store next-l X into the idle buffer
        if (l < NL - 1) {
            *(us8*)(d1 + (cur ^ 1) * 2304) = vn1;
            #pragma unroll
            for (int e = 0; e < 8; e++) xa1[e] += bfh2f(vn1[e]);
            if (t < 112) {
                *(us8*)(d2 + (cur ^ 1) * 2304) = vn2;
                #pragma unroll
                for (int e = 0; e < 8; e++) xa2[e] += bfh2f(vn2[e]);
            }
        }
        __syncthreads();   // P ready

        // --- phase B: att(mt,nt) += X^T @ P, K = 64 ---
        #pragma unroll
        for (int s = 0; s < 2; s++) {
            int aoff = (mt * 16 + lr) * 72 + 32 * s + 8 * lg;
            int boff = (nt * 16 + lr) * 72 + 32 * s + 8 * lg;
            bf16x8 ah = *(const bf16x8*)(xh + aoff);
            bf16x8 al = *(const bf16x8*)(xl + aoff);
            bf16x8 bh = *(const bf16x8*)(sPh + boff);
            bf16x8 bl = *(const bf16x8*)(sPl + boff);
            attC = __builtin_amdgcn_mfma_f32_16x16x32_bf16(ah, bh, attC, 0, 0, 0);
            attC = __builtin_amdgcn_mfma_f32_16x16x32_bf16(ah, bl, attC, 0, 0, 0);
            attC = __builtin_amdgcn_mfma_f32_16x16x32_bf16(al, bh, attC, 0, 0, 0);
        }
    }

    // --- rank-1 correction terms from hi+lo column sums ---
    if (t < 184) {
        #pragma unroll
        for (int e = 0; e < 8; e++) sxs[(8 * k1 + e) * 25 + n1] = xa1[e];
    }
    __syncthreads();
    if (t >= 184) {
        #pragma unroll
        for (int e = 0; e < 8; e++) sxs[(8 * k1 + e) * 25 + n1] += xa1[e];
    }
    if (t < 112) {
        #pragma unroll
        for (int e = 0; e < 8; e++) sxs[(8 * k2 + e) * 25 + n2] += xa2[e];
    }
    __syncthreads();
    if (t < 23) {
        float a = 0.f;
        const float* u = ws + OFF_U1 + h * 64;
        for (int c = 0; c < 64; c++) a += u[c] * sxs[c * 25 + t];
        sA1[t] = a;
    } else if (t >= 32 && t < 55) {
        int n = t - 32;
        float a = 0.f;
        const float* u = ws + OFF_U2 + h * 64;
        for (int c = 0; c < 64; c++) a += u[c] * sxs[c * 25 + n];
        sA2[n] = a;
    }
    __syncthreads();

    float sh = ws[OFF_S + h];
    float* o = ws + OFF_ATTM + (size_t)b * HF + h * NSQ;
    int n = nt * 16 + lr;
    if (n < 23) {
        #pragma unroll
        for (int r = 0; r < 4; r++) {
            int m = mt * 16 + 4 * lg + r;
            if (m < 23)
                o[m * 23 + n] = (attC[r] + sA1[n] + sA2[m] + 35.f * sh) * (1.f / 2240.f);
        }
    }
}

// ---------------------------------------------------------------------------
// Kernel 3: BN batch statistics; 25 blocks x (64 features x 8 batch-groups).
__global__ __launch_bounds__(512) void k_bn(float* __restrict__ ws) {
    int t = threadIdx.x;
    int fi = t & 63, bg = t >> 6;
    int f = blockIdx.x * 64 + fi;
    __shared__ float rs[8][64], rs2[8][64];
    float s = 0.f, s2 = 0.f;
    if (f < HF) {
        const float* p = ws + OFF_ATTM + f + (size_t)bg * 32 * HF;
        for (int b = 0; b < 32; b++) {
            float v = p[b * HF];
            s += v; s2 += v * v;
        }
    }
    rs[bg][fi] = s; rs2[bg][fi] = s2;
    __syncthreads();
    if (bg == 0 && f < HF) {
        float ts = 0.f, ts2 = 0.f;
        #pragma unroll
        for (int g = 0; g < 8; g++) { ts += rs[g][fi]; ts2 += rs2[g][fi]; }
        float mean = ts * (1.f / 256.f);
        float var  = ts2 * (1.f / 256.f) - mean * mean;
        ws[OFF_MEAN + f] = mean;
        ws[OFF_RSTD + f] = rsqrtf(var + 1e-5f);
    }
}

// ---------------------------------------------------------------------------
// Kernel 4: normalize, softmax over rows, A = A_ske + att + A_adp.
__global__ __launch_bounds__(256) void k_adp(const float* __restrict__ gamma,
                                             const float* __restrict__ beta,
                                             const float* __restrict__ att,
                                             const float* __restrict__ aske,
                                             float* __restrict__ ws) {
    int b = blockIdx.x, h = blockIdx.y, t = threadIdx.x;
    __shared__ float sv[529];
    const float* am   = ws + OFF_ATTM + b * HF + h * NSQ;
    const float* mean = ws + OFF_MEAN + h * NSQ;
    const float* rstd = ws + OFF_RSTD + h * NSQ;
    for (int i = t; i < 529; i += 256) {
        sv[i] = (am[i] - mean[i]) * rstd[i] * gamma[h * NSQ + i] + beta[h * NSQ + i];
    }
    __syncthreads();
    if (t < 23) {
        float mx = -1e30f;
        #pragma unroll
        for (int m = 0; m < 23; m++) mx = fmaxf(mx, sv[m * 23 + t]);
        float e[23];
        float sum = 0.f;
        #pragma unroll
        for (int m = 0; m < 23; m++) {
            float v = __expf(sv[m * 23 + t] - mx);
            e[m] = v; sum += v;
        }
        float inv = 1.f / sum;
        #pragma unroll
        for (int m = 0; m < 23; m++) sv[m * 23 + t] = e[m] * inv;
    }
    __syncthreads();
    float* o = ws + OFF_A + b * HF + h * NSQ;
    for (int i = t; i < 529; i += 256) {
        o[i] = sv[i] + aske[h * NSQ + i] + att[h * NSQ + i];
    }
}

// ---------------------------------------------------------------------------
// Kernel 5 (fused GCN + temporal FC), one block per batch b, 8 waves.
// Y = sum_h (MW[h] @ X) @ A[h]. T14 staging; sT stride 44.
// FC accumulated in registers as FOUR NAMED arrays acc0..acc3, every access
// compile-time-constant (rule #20: runtime-indexed arrays go to scratch —
// round-6 lesson: the rolled epilogue's acc[r] cost 2.6 GB of spill traffic).
// Epilogue fully unrolled via macro so r is a literal.
#define STS 44
__global__ __launch_bounds__(512, 2) void k_fused(float* __restrict__ ws,
                                                  const float* __restrict__ wseq,
                                                  const float* __restrict__ biasp,
                                                  float* __restrict__ out) {
    const int b = blockIdx.x, t = threadIdx.x;
    const int lane = t & 63;
    const int w = __builtin_amdgcn_readfirstlane(t >> 6);   // 0..7
    const int lg = lane >> 4, lr = lane & 15;
    const int nt = w >> 2, ot = w & 3;     // phase A' tile (n-tile, o-tile)
    const int ot2 = w >> 1, mt = w & 1;    // phase B' tile (o-tile, m-tile)

    __shared__ __align__(16) unsigned short sXh[32 * 72], sXl[32 * 72];
    __shared__ __align__(16) unsigned short sAT[3][2][32 * 40];  // A^T [m][n] hi/lo
    __shared__ __align__(16) unsigned short sT[3][64 * STS];     // T [o][n] hi only
    __shared__ __align__(16) float sEp[16 * 23 * 36];            // epilogue [oi][m][lp pad36]

    const unsigned short* xthl = (const unsigned short*)(ws + OFF_XTB);
    const float* Ab  = ws + OFF_A + (size_t)b * HF;

    // ---- one-time: zero sX rows 23..31 (they feed phase B's K-dim via T) ----
    for (int i = t; i < 9 * 72; i += 512) {
        sXh[23 * 72 + i] = 0;
        sXl[23 * 72 + i] = 0;
    }
    // ---- one-time staging (first in-loop barrier fences all of it) ----
    for (int i = t; i < 3 * 1280; i += 512) {
        int h = i / 1280, r2 = i - h * 1280, m = r2 / 40, n = r2 - m * 40;
        float v = (n < 23 && m < 23) ? Ab[h * 529 + n * 23 + m] : 0.f;
        unsigned short hb = bfh(v);
        sAT[h][0][m * 40 + n] = hb;
        sAT[h][1][m * 40 + n] = bfh(v - bfh2f(hb));
    }

    // ---- MW fragments as phase-A' B-operand (MW^T cols o = MW rows o) ----
    const unsigned short* mwh = (const unsigned short*)(ws + OFF_MWH);
    const unsigned short* mwl = (const unsigned short*)(ws + OFF_MWL);
    bf16x8 fwh[3][2], fwl[3][2];
    #pragma unroll
    for (int h = 0; h < 3; h++)
        #pragma unroll
        for (int s = 0; s < 2; s++) {
            int off = h * 4096 + (16 * ot + lr) * 64 + 32 * s + 8 * lg;
            fwh[h][s] = *(const bf16x8*)(mwh + off);
            fwl[h][s] = *(const bf16x8*)(mwl + off);
        }
    float4 mbsv = *(const float4*)(ws + OFF_MBS + 16 * ot2 + 4 * lg);
    float mb4[4] = {mbsv.x, mbsv.y, mbsv.z, mbsv.w};

    // staging chunk decomposition (t < 368 active)
    const int p1 = t / 184, r1 = t - p1 * 184;
    const int n1 = r1 >> 3, k1 = r1 & 7;
    unsigned short* d1 = (p1 ? sXl : sXh) + n1 * 72 + 8 * k1;

    const f32x4 zf = {0.f, 0.f, 0.f, 0.f};

    // FC accumulators: four NAMED arrays, static indexing only
    float acc0[35], acc1[35], acc2[35], acc3[35];
    #pragma unroll
    for (int lp = 0; lp < 35; lp++) { acc0[lp] = 0.f; acc1[lp] = 0.f; acc2[lp] = 0.f; acc3[lp] = 0.f; }

    // prologue: stage l = 0
    if (t < 368) {
        const us8* g = (const us8*)(xthl + (size_t)(b * NL) * 2944);
        *(us8*)d1 = g[t];
    }

    #pragma unroll 1
    for (int l = 0; l < NL; l++) {
        __syncthreads();   // sX(l) ready

        // issue next-l load early (reg-carry; written after bar2)
        us8 vn;
        if (l < NL - 1 && t < 368) {
            const us8* g = (const us8*)(xthl + (size_t)(b * NL + l + 1) * 2944);
            vn = g[t];
        }

        // ---- phase A': T^T = X^T @ MW^T per h; M=n, N=o, K=c=64 ----
        bf16x8 xh0 = *(const bf16x8*)(sXh + (16 * nt + lr) * 72 + 8 * lg);
        bf16x8 xh1 = *(const bf16x8*)(sXh + (16 * nt + lr) * 72 + 32 + 8 * lg);
        bf16x8 xl0 = *(const bf16x8*)(sXl + (16 * nt + lr) * 72 + 8 * lg);
        bf16x8 xl1 = *(const bf16x8*)(sXl + (16 * nt + lr) * 72 + 32 + 8 * lg);
        #pragma unroll
        for (int h = 0; h < 3; h++) {
            f32x4 cH = __builtin_amdgcn_mfma_f32_16x16x32_bf16(xh0, fwh[h][0], zf, 0, 0, 0);
            cH = __builtin_amdgcn_mfma_f32_16x16x32_bf16(xh1, fwh[h][1], cH, 0, 0, 0);
            f32x4 cC = __builtin_amdgcn_mfma_f32_16x16x32_bf16(xh0, fwl[h][0], zf, 0, 0, 0);
            cC = __builtin_amdgcn_mfma_f32_16x16x32_bf16(xh1, fwl[h][1], cC, 0, 0, 0);
            cC = __builtin_amdgcn_mfma_f32_16x16x32_bf16(xl0, fwh[h][0], cC, 0, 0, 0);
            cC = __builtin_amdgcn_mfma_f32_16x16x32_bf16(xl1, fwh[h][1], cC, 0, 0, 0);
            us4 t4;
            #pragma unroll
            for (int r = 0; r < 4; r++) t4[r] = bf16rn(cH[r] + cC[r]);
            *(us4*)(&sT[h][(16 * ot + lr) * STS + 16 * nt + 4 * lg]) = t4;
        }
        __syncthreads();   // T ready; all phase-A' sX reads done

        // ---- phase B': Y(ot2,mt) = sum_h T[h] @ A[h]; K = n = 32 ----
        f32x4 Yh = zf, Yc = zf;
        #pragma unroll
        for (int h = 0; h < 3; h++) {
            union { bf16x8 v; us4 q[2]; } tu;
            tu.q[0] = *(const us4*)(&sT[h][(16 * ot2 + lr) * STS + 8 * lg]);
            tu.q[1] = *(const us4*)(&sT[h][(16 * ot2 + lr) * STS + 8 * lg + 4]);
            bf16x8 ah = *(const bf16x8*)(&sAT[h][0][(16 * mt + lr) * 40 + 8 * lg]);
            bf16x8 al = *(const bf16x8*)(&sAT[h][1][(16 * mt + lr) * 40 + 8 * lg]);
            Yh = __builtin_amdgcn_mfma_f32_16x16x32_bf16(tu.v, ah, Yh, 0, 0, 0);
            Yc = __builtin_amdgcn_mfma_f32_16x16x32_bf16(tu.v, al, Yc, 0, 0, 0);
        }

        // ---- FC accumulate in registers: accR[lp] += y_R * W[l][lp] ----
        float yv0 = Yh[0] + Yc[0] + mb4[0];
        float yv1 = Yh[1] + Yc[1] + mb4[1];
        float yv2 = Yh[2] + Yc[2] + mb4[2];
        float yv3 = Yh[3] + Yc[3] + mb4[3];
        const float* wr = wseq + l * 35;   // lane-uniform -> scalar loads
        #pragma unroll
        for (int lp = 0; lp < 35; lp++) {
            float wv = wr[lp];
            acc0[lp] += yv0 * wv;
            acc1[lp] += yv1 * wv;
            acc2[lp] += yv2 * wv;
            acc3[lp] += yv3 * wv;
        }

        // write-late: store next-l X (safe: bar2 proved all A' readers done)
        if (l < NL - 1 && t < 368) *(us8*)d1 = vn;
    }

    // ---- epilogue: 4 r-chunks through LDS, coalesced out writes. r is a
    // compile-time literal in each expansion (no dynamic acc indexing). ----
    const int oi = 4 * ot2 + lg;       // o = 4*oi + R
    const int m  = 16 * mt + lr;
#define EPILOG(R, ACC)                                                         \
    __syncthreads();                                                           \
    if (m < 23) {                                                              \
        float* ep = sEp + (oi * 23 + m) * 36;                                  \
        _Pragma("unroll")                                                      \
        for (int lp = 0; lp < 35; lp++) ep[lp] = ACC[lp] + biasp[lp];          \
    }                                                                          \
    __syncthreads();                                                           \
    for (int i = t; i < 16 * 805; i += 512) {                                  \
        int o16 = i / 805, rem = i - o16 * 805;                                \
        int mm = rem / 35, lp = rem - mm * 35;                                 \
        out[((size_t)(b * 1472 + (4 * o16 + R) * 23)) * 35 + rem] =            \
            sEp[(o16 * 23 + mm) * 36 + lp];                                    \
    }
    EPILOG(0, acc0)
    EPILOG(1, acc1)
    EPILOG(2, acc2)
    EPILOG(3, acc3)
#undef EPILOG
}

// ---------------------------------------------------------------------------
extern "C" void kernel_launch(void* const* d_in, const int* in_sizes, int n_in,
                              void* d_out, int out_size, void* d_ws, size_t ws_size,
                              hipStream_t stream) {
    const float* x    = (const float*)d_in[0];
    const float* cw1  = (const float*)d_in[1];
    const float* cb1  = (const float*)d_in[2];
    const float* cw2  = (const float*)d_in[3];
    const float* cb2  = (const float*)d_in[4];
    const float* gam  = (const float*)d_in[5];
    const float* bet  = (const float*)d_in[6];
    const float* mw   = (const float*)d_in[7];
    const float* mb   = (const float*)d_in[8];
    const float* att  = (const float*)d_in[9];
    const float* aske = (const float*)d_in[10];
    const float* wsq  = (const float*)d_in[11];
    const float* bias = (const float*)d_in[12];
    float* ws = (float*)d_ws;
    float* out = (float*)d_out;

    hipLaunchKernelGGL(k_prep, dim3(4),       dim3(256),  0, stream, cw1, cb1, cw2, cb2, mw, mb, ws);
    hipLaunchKernelGGL(k_xt,   dim3(256),     dim3(1024), 0, stream, x, ws);
    hipLaunchKernelGGL(k_attm, dim3(256, 3),  dim3(256),  0, stream, ws);
    hipLaunchKernelGGL(k_bn,   dim3(25),      dim3(512),  0, stream, ws);
    hipLaunchKernelGGL(k_adp,  dim3(256, 3),  dim3(256),  0, stream, gam, bet, att, aske, ws);
    hipLaunchKernelGGL(k_fused, dim3(256),    dim3(512),  0, stream, ws, wsq, bias, out);
}

// Round 8
// 264.489 us; speedup vs baseline: 2.2827x; 1.0121x over previous
//
#include <hip/hip_runtime.h>
#include <hip/hip_bf16.h>

typedef __hip_bfloat16 bf16;
typedef __attribute__((ext_vector_type(8))) short bf16x8;
typedef __attribute__((ext_vector_type(4))) float f32x4;
typedef __attribute__((ext_vector_type(4))) unsigned short us4;
typedef __attribute__((ext_vector_type(8))) unsigned short us8;

// Problem constants
#define NB   256           // batch
#define NN   23            // nodes
#define NL   35            // seq len
#define NNL  805           // NN*NL
#define CNL  51520         // NC*NNL (per-batch x elements)
#define NSQ  529           // NN*NN
#define HF   1587          // NH*NSQ
#define NCN  1472          // 64*23 (one X_l slice)

// ws layout (float offsets)
#define OFF_W     0         // [3][64][64]
#define OFF_U1    12288
#define OFF_U2    12480
#define OFF_S     12672
#define OFF_ATTM  12800     // [256][1587]
#define OFF_MEAN  419072
#define OFF_RSTD  420672
#define OFF_A     422272    // [256][1587] -> 828544
#define OFF_MWH   828544    // mw bf16 hi [3][64o][64c] (12288 shorts)
#define OFF_MWL   834688    // mw bf16 lo
#define OFF_MBS   840832    // mbsum[64] -> pad 840960
#define OFF_XTB   840960    // X^T bf16 hi/lo [256][35][2 planes][23n][64c]

// split-bf16 helpers: x = hi + lo, each exactly representable in bf16
__device__ inline unsigned short bfh(float x) {
    unsigned u = __float_as_uint(x);
    return (unsigned short)((u + 0x7FFFu + ((u >> 16) & 1u)) >> 16);  // RNE
}
__device__ inline float bfh2f(unsigned short h) {
    return __uint_as_float(((unsigned)h) << 16);
}
// RNE f32->bf16 via HW cvt (numerically identical to bfh for finite inputs)
__device__ inline unsigned short bf16rn(float x) {
    __hip_bfloat16 h = __float2bfloat16(x);
    return __builtin_bit_cast(unsigned short, h);
}

// ---------------------------------------------------------------------------
// Kernel 0: transpose x[b][c][n][l] -> X^T bf16 hi/lo [b][l][p][n][c].
// Quarter-channel blocks: grid (256,4), 51.5 KB LDS -> 3 blocks/CU.
__global__ __launch_bounds__(512) void k_xt(const float* __restrict__ x,
                                            float* __restrict__ ws) {
    int b = blockIdx.x, ch = blockIdx.y, t = threadIdx.x;  // ch: 16-channel group
    __shared__ float sx[16 * 805];       // 51.5 KB
    const float* xb = x + b * CNL + ch * (16 * 805);
    unsigned short* xo = (unsigned short*)(ws + OFF_XTB) + (size_t)b * NL * 2944;
    for (int i = t; i < 16 * 805; i += 512) sx[i] = xb[i];
    __syncthreads();
    // item = (l, n, k2): k2 selects an 8-channel chunk; global c = 16ch + 8k2 + e
    for (int item = t; item < 35 * 46; item += 512) {
        int l = item / 46, rem = item - l * 46;
        int n = rem >> 1, k2 = rem & 1;
        us8 hi, lo;
        #pragma unroll
        for (int e = 0; e < 8; e++) {
            float v = sx[(8 * k2 + e) * 805 + n * 35 + l];
            unsigned short hb = bfh(v);
            hi[e] = hb;
            lo[e] = bfh(v - bfh2f(hb));
        }
        unsigned short* dst = xo + (size_t)l * 2944 + n * 64 + 8 * (2 * ch + k2);
        *(us8*)(dst) = hi;           // plane hi
        *(us8*)(dst + 1472) = lo;    // plane lo
    }
}

// ---------------------------------------------------------------------------
// Kernel 1: fold projection weights; block 3 converts mw to bf16 hi/lo + mb sum.
__global__ __launch_bounds__(256) void k_prep(const float* __restrict__ cw1,
                                              const float* __restrict__ cb1,
                                              const float* __restrict__ cw2,
                                              const float* __restrict__ cb2,
                                              const float* __restrict__ mw,
                                              const float* __restrict__ mb,
                                              float* __restrict__ ws) {
    int h = blockIdx.x, t = threadIdx.x;
    __shared__ float s1[4096], s2[4096];
    if (h < 3) {
        for (int i = t; i < 4096; i += 256) {
            s1[i] = cw1[h * 4096 + i];
            s2[i] = cw2[h * 4096 + i];
        }
        __syncthreads();
        for (int i = t; i < 4096; i += 256) {
            int c2 = i >> 6, c1 = i & 63;
            float acc = 0.f;
            for (int o = 0; o < 64; o++) acc += s2[o * 64 + c2] * s1[o * 64 + c1];
            ws[OFF_W + h * 4096 + i] = acc;
        }
        if (t < 64) {
            float a = 0.f, b2 = 0.f;
            for (int o = 0; o < 64; o++) {
                a  += cb2[h * 64 + o] * s1[o * 64 + t];
                b2 += cb1[h * 64 + o] * s2[o * 64 + t];
            }
            ws[OFF_U1 + h * 64 + t] = a;
            ws[OFF_U2 + h * 64 + t] = b2;
        }
        if (t == 0) {
            float a = 0.f;
            for (int o = 0; o < 64; o++) a += cb1[h * 64 + o] * cb2[h * 64 + o];
            ws[OFF_S + h] = a;
        }
    } else {
        unsigned short* mh = (unsigned short*)(ws + OFF_MWH);
        unsigned short* ml = (unsigned short*)(ws + OFF_MWL);
        for (int i = t; i < 12288; i += 256) {
            float v = mw[i];                 // layout [h][o][c]
            unsigned short hb = bfh(v);
            mh[i] = hb;
            ml[i] = bfh(v - bfh2f(hb));
        }
        if (t < 64) ws[OFF_MBS + t] = mb[t] + mb[64 + t] + mb[128 + t];
    }
}

// ---------------------------------------------------------------------------
// Kernel 2 (MFMA): att_m[b,h,m,n] = (sum_l X_l^T W X_l + a1[n] + a2[m] + 35*s)/2240
// T14: issue l+1 loads right after bar1; write idle buffer after phase A.
__global__ __launch_bounds__(256) void k_attm(float* __restrict__ ws) {
    const int b = blockIdx.x, h = blockIdx.y, t = threadIdx.x;
    const int lane = t & 63;
    const int w = __builtin_amdgcn_readfirstlane(t >> 6);   // wave 0..3
    const int lg = lane >> 4;      // k-group 0..3
    const int lr = lane & 15;      // row/col within 16-tile

    __shared__ unsigned short sXh[2][32 * 72];   // X^T hi, double-buffered
    __shared__ unsigned short sXl[2][32 * 72];   // X^T lo
    __shared__ unsigned short sPh[32 * 72];      // P^T hi  [n][c2]
    __shared__ unsigned short sPl[32 * 72];      // P^T lo
    __shared__ float sxs[64 * 25];               // sum_l X  [c][n], stride 25
    __shared__ float sA1[23], sA2[23];

    const unsigned short* xthl = (const unsigned short*)(ws + OFF_XTB);

    // --- W fragments (phase-A A-operand), hoisted: rows 16w+lr, split hi/lo ---
    bf16x8 wh[2], wl[2];
    {
        const float* Wg = ws + OFF_W + h * 4096 + (16 * w + lr) * 64;
        #pragma unroll
        for (int s = 0; s < 2; s++) {
            const float* p = Wg + 32 * s + 8 * lg;
            float4 v0 = *(const float4*)(p);
            float4 v1 = *(const float4*)(p + 4);
            float vv[8] = {v0.x, v0.y, v0.z, v0.w, v1.x, v1.y, v1.z, v1.w};
            #pragma unroll
            for (int e = 0; e < 8; e++) {
                unsigned short hb = bfh(vv[e]);
                wh[s][e] = (short)hb;
                wl[s][e] = (short)bfh(vv[e] - bfh2f(hb));
            }
        }
    }

    // --- staging chunk decomposition (368 = 2 planes x 23 rows x 8 chunks) ---
    const int j1 = t;                              // chunk 1 (all threads)
    const int p1 = j1 / 184, r1 = j1 - p1 * 184;
    const int n1 = r1 >> 3, k1 = r1 & 7;
    unsigned short* d1 = (p1 ? sXl[0] : sXh[0]) + n1 * 72 + 8 * k1;
    const int j2 = 256 + t;                        // chunk 2 (t<112, plane lo)
    const int r2 = j2 - 184;
    const int n2 = r2 >> 3, k2 = r2 & 7;
    unsigned short* d2 = sXl[0] + n2 * 72 + 8 * k2;

    const int mt = w >> 1, nt = w & 1;             // phase-B tile
    f32x4 attC = {0.f, 0.f, 0.f, 0.f};
    float xa1[8] = {0, 0, 0, 0, 0, 0, 0, 0};
    float xa2[8] = {0, 0, 0, 0, 0, 0, 0, 0};

    // --- prologue: stage l = 0 into buffer 0 ---
    {
        const us8* g = (const us8*)(xthl + (size_t)(b * NL) * 2944);
        us8 v1 = g[j1];
        *(us8*)(d1) = v1;
        #pragma unroll
        for (int e = 0; e < 8; e++) xa1[e] += bfh2f(v1[e]);
        if (t < 112) {
            us8 v2 = g[j2];
            *(us8*)(d2) = v2;
            #pragma unroll
            for (int e = 0; e < 8; e++) xa2[e] += bfh2f(v2[e]);
        }
    }

    #pragma unroll 1
    for (int l = 0; l < NL; l++) {
        const int cur = l & 1;
        __syncthreads();   // buf[cur] ready; prev-iter consumers done

        // issue next-l loads early (latency hides under phase A)
        us8 vn1, vn2;
        if (l < NL - 1) {
            const us8* g = (const us8*)(xthl + (size_t)(b * NL + l + 1) * 2944);
            vn1 = g[j1];
            if (t < 112) vn2 = g[j2];
        }

        const unsigned short* xh = sXh[cur];
        const unsigned short* xl = sXl[cur];

        // --- phase A: P rows [16w,16w+16) x n-tiles {0,1}, K = 64 ---
        f32x4 pc[2];
        #pragma unroll
        for (int ntt = 0; ntt < 2; ntt++) {
            f32x4 c = {0.f, 0.f, 0.f, 0.f};
            #pragma unroll
            for (int s = 0; s < 2; s++) {
                int off = (ntt * 16 + lr) * 72 + 32 * s + 8 * lg;
                bf16x8 bh = *(const bf16x8*)(xh + off);
                bf16x8 bl = *(const bf16x8*)(xl + off);
                c = __builtin_amdgcn_mfma_f32_16x16x32_bf16(wh[s], bh, c, 0, 0, 0);
                c = __builtin_amdgcn_mfma_f32_16x16x32_bf16(wh[s], bl, c, 0, 0, 0);
                c = __builtin_amdgcn_mfma_f32_16x16x32_bf16(wl[s], bh, c, 0, 0, 0);
            }
            pc[ntt] = c;
        }
        #pragma unroll
        for (int ntt = 0; ntt < 2; ntt++) {
            int n = ntt * 16 + lr;
            int c2 = 16 * w + 4 * lg;
            us4 ph4, pl4;
            #pragma unroll
            for (int r = 0; r < 4; r++) {
                float v = pc[ntt][r];
                unsigned short hb = bf16rn(v);
                ph4[r] = hb;
                pl4[r] = bf16rn(v - bfh2f(hb));
            }
            *(us4*)(sPh + n * 72 + c2) = ph4;
            *(us4*)(sPl + n * 72 + c2) = pl4;
        }

        // write-late: store next-l X into the idle buffer
        if (l < NL - 1) {
            *(us8*)(d1 + (cur ^ 1) * 2304) = vn1;
            #pragma unroll
            for (int e = 0; e < 8; e++) xa1[e] += bfh2f(vn1[e]);
            if (t < 112) {
                *(us8*)(d2 + (cur ^ 1) * 2304) = vn2;
                #pragma unroll
                for (int e = 0; e < 8; e++) xa2[e] += bfh2f(vn2[e]);
            }
        }
        __syncthreads();   // P ready

        // --- phase B: att(mt,nt) += X^T @ P, K = 64 ---
        #pragma unroll
        for (int s = 0; s < 2; s++) {
            int aoff = (mt * 16 + lr) * 72 + 32 * s + 8 * lg;
            int boff = (nt * 16 + lr) * 72 + 32 * s + 8 * lg;
            bf16x8 ah = *(const bf16x8*)(xh + aoff);
            bf16x8 al = *(const bf16x8*)(xl + aoff);
            bf16x8 bh = *(const bf16x8*)(sPh + boff);
            bf16x8 bl = *(const bf16x8*)(sPl + boff);
            attC = __builtin_amdgcn_mfma_f32_16x16x32_bf16(ah, bh, attC, 0, 0, 0);
            attC = __builtin_amdgcn_mfma_f32_16x16x32_bf16(ah, bl, attC, 0, 0, 0);
            attC = __builtin_amdgcn_mfma_f32_16x16x32_bf16(al, bh, attC, 0, 0, 0);
        }
    }

    // --- rank-1 correction terms from hi+lo column sums ---
    if (t < 184) {
        #pragma unroll
        for (int e = 0; e < 8; e++) sxs[(8 * k1 + e) * 25 + n1] = xa1[e];
    }
    __syncthreads();
    if (t >= 184) {
        #pragma unroll
        for (int e = 0; e < 8; e++) sxs[(8 * k1 + e) * 25 + n1] += xa1[e];
    }
    if (t < 112) {
        #pragma unroll
        for (int e = 0; e < 8; e++) sxs[(8 * k2 + e) * 25 + n2] += xa2[e];
    }
    __syncthreads();
    if (t < 23) {
        float a = 0.f;
        const float* u = ws + OFF_U1 + h * 64;
        for (int c = 0; c < 64; c++) a += u[c] * sxs[c * 25 + t];
        sA1[t] = a;
    } else if (t >= 32 && t < 55) {
        int n = t - 32;
        float a = 0.f;
        const float* u = ws + OFF_U2 + h * 64;
        for (int c = 0; c < 64; c++) a += u[c] * sxs[c * 25 + n];
        sA2[n] = a;
    }
    __syncthreads();

    float sh = ws[OFF_S + h];
    float* o = ws + OFF_ATTM + (size_t)b * HF + h * NSQ;
    int n = nt * 16 + lr;
    if (n < 23) {
        #pragma unroll
        for (int r = 0; r < 4; r++) {
            int m = mt * 16 + 4 * lg + r;
            if (m < 23)
                o[m * 23 + n] = (attC[r] + sA1[n] + sA2[m] + 35.f * sh) * (1.f / 2240.f);
        }
    }
}

// ---------------------------------------------------------------------------
// Kernel 3: BN batch statistics; 25 blocks x (64 features x 8 batch-groups).
__global__ __launch_bounds__(512) void k_bn(float* __restrict__ ws) {
    int t = threadIdx.x;
    int fi = t & 63, bg = t >> 6;
    int f = blockIdx.x * 64 + fi;
    __shared__ float rs[8][64], rs2[8][64];
    float s = 0.f, s2 = 0.f;
    if (f < HF) {
        const float* p = ws + OFF_ATTM + f + (size_t)bg * 32 * HF;
        for (int b = 0; b < 32; b++) {
            float v = p[b * HF];
            s += v; s2 += v * v;
        }
    }
    rs[bg][fi] = s; rs2[bg][fi] = s2;
    __syncthreads();
    if (bg == 0 && f < HF) {
        float ts = 0.f, ts2 = 0.f;
        #pragma unroll
        for (int g = 0; g < 8; g++) { ts += rs[g][fi]; ts2 += rs2[g][fi]; }
        float mean = ts * (1.f / 256.f);
        float var  = ts2 * (1.f / 256.f) - mean * mean;
        ws[OFF_MEAN + f] = mean;
        ws[OFF_RSTD + f] = rsqrtf(var + 1e-5f);
    }
}

// ---------------------------------------------------------------------------
// Kernel 4: normalize, softmax over rows, A = A_ske + att + A_adp.
__global__ __launch_bounds__(256) void k_adp(const float* __restrict__ gamma,
                                             const float* __restrict__ beta,
                                             const float* __restrict__ att,
                                             const float* __restrict__ aske,
                                             float* __restrict__ ws) {
    int b = blockIdx.x, h = blockIdx.y, t = threadIdx.x;
    __shared__ float sv[529];
    const float* am   = ws + OFF_ATTM + b * HF + h * NSQ;
    const float* mean = ws + OFF_MEAN + h * NSQ;
    const float* rstd = ws + OFF_RSTD + h * NSQ;
    for (int i = t; i < 529; i += 256) {
        sv[i] = (am[i] - mean[i]) * rstd[i] * gamma[h * NSQ + i] + beta[h * NSQ + i];
    }
    __syncthreads();
    if (t < 23) {
        float mx = -1e30f;
        #pragma unroll
        for (int m = 0; m < 23; m++) mx = fmaxf(mx, sv[m * 23 + t]);
        float e[23];
        float sum = 0.f;
        #pragma unroll
        for (int m = 0; m < 23; m++) {
            float v = __expf(sv[m * 23 + t] - mx);
            e[m] = v; sum += v;
        }
        float inv = 1.f / sum;
        #pragma unroll
        for (int m = 0; m < 23; m++) sv[m * 23 + t] = e[m] * inv;
    }
    __syncthreads();
    float* o = ws + OFF_A + b * HF + h * NSQ;
    for (int i = t; i < 529; i += 256) {
        o[i] = sv[i] + aske[h * NSQ + i] + att[h * NSQ + i];
    }
}

// ---------------------------------------------------------------------------
// Kernel 5 (fused GCN + temporal FC), one block per batch b, 8 waves.
// ROUND-5 VERSION (measured 60 us) — sY LDS buffer + post-loop MFMA FC.
// (Round-7 lesson: in-loop register FC at 2 waves/SIMD regressed to 74 us —
//  140-float acc spilled to AGPR half at the 256-VGPR cap.)
#define SYS 38
#define STS 44
__global__ __launch_bounds__(512, 2) void k_fused(float* __restrict__ ws,
                                                  const float* __restrict__ wseq,
                                                  const float* __restrict__ biasp,
                                                  float* __restrict__ out) {
    const int b = blockIdx.x, t = threadIdx.x;
    const int lane = t & 63;
    const int w = __builtin_amdgcn_readfirstlane(t >> 6);   // 0..7
    const int lg = lane >> 4, lr = lane & 15;
    const int nt = w >> 2, ot = w & 3;     // phase A' tile (n-tile, o-tile)
    const int ot2 = w >> 1, mt = w & 1;    // phase B' tile (o-tile, m-tile)

    __shared__ __align__(16) unsigned short sXh[32 * 72], sXl[32 * 72];
    __shared__ __align__(16) unsigned short sAT[3][2][32 * 40];  // A^T [m][n] hi/lo
    __shared__ __align__(16) unsigned short sT[3][64 * STS];     // T [o][n] hi only
    __shared__ __align__(16) unsigned short sY[1472 * SYS];      // y bf16 [p][l]
    __shared__ __align__(16) unsigned short sWTh[48 * 40], sWTl[48 * 40]; // W^T [lp][l<32]
    __shared__ float sWt[3 * 35];        // W rows l=32..34
    __shared__ float sBias[35];

    const unsigned short* xthl = (const unsigned short*)(ws + OFF_XTB);
    const float* Ab  = ws + OFF_A + (size_t)b * HF;

    // ---- one-time: zero sX rows 23..31 (they feed phase B's K-dim via T) ----
    for (int i = t; i < 9 * 72; i += 512) {
        sXh[23 * 72 + i] = 0;
        sXl[23 * 72 + i] = 0;
    }
    // ---- one-time staging (first in-loop barrier fences all of it) ----
    for (int i = t; i < 3 * 1280; i += 512) {
        int h = i / 1280, r2 = i - h * 1280, m = r2 / 40, n = r2 - m * 40;
        float v = (n < 23 && m < 23) ? Ab[h * 529 + n * 23 + m] : 0.f;
        unsigned short hb = bfh(v);
        sAT[h][0][m * 40 + n] = hb;
        sAT[h][1][m * 40 + n] = bfh(v - bfh2f(hb));
    }
    for (int i = t; i < 48 * 40; i += 512) {
        int lp = i / 40, l = i - lp * 40;
        float v = (lp < 35 && l < 32) ? wseq[l * 35 + lp] : 0.f;
        unsigned short hb = bfh(v);
        sWTh[i] = hb;
        sWTl[i] = bfh(v - bfh2f(hb));
    }
    if (t < 105) sWt[t] = wseq[(32 + t / 35) * 35 + (t % 35)];
    if (t >= 128 && t < 163) sBias[t - 128] = biasp[t - 128];

    // ---- MW fragments as phase-A' B-operand (MW^T cols o = MW rows o) ----
    const unsigned short* mwh = (const unsigned short*)(ws + OFF_MWH);
    const unsigned short* mwl = (const unsigned short*)(ws + OFF_MWL);
    bf16x8 fwh[3][2], fwl[3][2];
    #pragma unroll
    for (int h = 0; h < 3; h++)
        #pragma unroll
        for (int s = 0; s < 2; s++) {
            int off = h * 4096 + (16 * ot + lr) * 64 + 32 * s + 8 * lg;
            fwh[h][s] = *(const bf16x8*)(mwh + off);
            fwl[h][s] = *(const bf16x8*)(mwl + off);
        }
    float4 mbsv = *(const float4*)(ws + OFF_MBS + 16 * ot2 + 4 * lg);
    float mb4[4] = {mbsv.x, mbsv.y, mbsv.z, mbsv.w};

    // staging chunk decomposition (t < 368 active)
    const int p1 = t / 184, r1 = t - p1 * 184;
    const int n1 = r1 >> 3, k1 = r1 & 7;
    unsigned short* d1 = (p1 ? sXl : sXh) + n1 * 72 + 8 * k1;

    const f32x4 zf = {0.f, 0.f, 0.f, 0.f};

    // prologue: stage l = 0
    if (t < 368) {
        const us8* g = (const us8*)(xthl + (size_t)(b * NL) * 2944);
        *(us8*)d1 = g[t];
    }

    #pragma unroll 1
    for (int l = 0; l < NL; l++) {
        __syncthreads();   // sX(l) ready

        // issue next-l load early (reg-carry; written after bar2)
        us8 vn;
        if (l < NL - 1 && t < 368) {
            const us8* g = (const us8*)(xthl + (size_t)(b * NL + l + 1) * 2944);
            vn = g[t];
        }

        // ---- phase A': T^T = X^T @ MW^T per h; M=n, N=o, K=c=64 ----
        bf16x8 xh0 = *(const bf16x8*)(sXh + (16 * nt + lr) * 72 + 8 * lg);
        bf16x8 xh1 = *(const bf16x8*)(sXh + (16 * nt + lr) * 72 + 32 + 8 * lg);
        bf16x8 xl0 = *(const bf16x8*)(sXl + (16 * nt + lr) * 72 + 8 * lg);
        bf16x8 xl1 = *(const bf16x8*)(sXl + (16 * nt + lr) * 72 + 32 + 8 * lg);
        #pragma unroll
        for (int h = 0; h < 3; h++) {
            f32x4 cH = __builtin_amdgcn_mfma_f32_16x16x32_bf16(xh0, fwh[h][0], zf, 0, 0, 0);
            cH = __builtin_amdgcn_mfma_f32_16x16x32_bf16(xh1, fwh[h][1], cH, 0, 0, 0);
            f32x4 cC = __builtin_amdgcn_mfma_f32_16x16x32_bf16(xh0, fwl[h][0], zf, 0, 0, 0);
            cC = __builtin_amdgcn_mfma_f32_16x16x32_bf16(xh1, fwl[h][1], cC, 0, 0, 0);
            cC = __builtin_amdgcn_mfma_f32_16x16x32_bf16(xl0, fwh[h][0], cC, 0, 0, 0);
            cC = __builtin_amdgcn_mfma_f32_16x16x32_bf16(xl1, fwh[h][1], cC, 0, 0, 0);
            us4 t4;
            #pragma unroll
            for (int r = 0; r < 4; r++) t4[r] = bf16rn(cH[r] + cC[r]);
            *(us4*)(&sT[h][(16 * ot + lr) * STS + 16 * nt + 4 * lg]) = t4;
        }
        __syncthreads();   // T ready; all phase-A' sX reads done

        // ---- phase B': Y(ot2,mt) = sum_h T[h] @ A[h]; K = n = 32 ----
        f32x4 Yh = zf, Yc = zf;
        #pragma unroll
        for (int h = 0; h < 3; h++) {
            union { bf16x8 v; us4 q[2]; } tu;
            tu.q[0] = *(const us4*)(&sT[h][(16 * ot2 + lr) * STS + 8 * lg]);
            tu.q[1] = *(const us4*)(&sT[h][(16 * ot2 + lr) * STS + 8 * lg + 4]);
            bf16x8 ah = *(const bf16x8*)(&sAT[h][0][(16 * mt + lr) * 40 + 8 * lg]);
            bf16x8 al = *(const bf16x8*)(&sAT[h][1][(16 * mt + lr) * 40 + 8 * lg]);
            Yh = __builtin_amdgcn_mfma_f32_16x16x32_bf16(tu.v, ah, Yh, 0, 0, 0);
            Yc = __builtin_amdgcn_mfma_f32_16x16x32_bf16(tu.v, al, Yc, 0, 0, 0);
        }
        int m = 16 * mt + lr;
        if (m < 23) {
            #pragma unroll
            for (int r = 0; r < 4; r++) {
                int o = 16 * ot2 + 4 * lg + r;
                float yv = Yh[r] + Yc[r] + mb4[r];
                sY[(o * 23 + m) * SYS + l] = bf16rn(yv);
            }
        }

        // write-late: store next-l X (safe: bar2 proved all A' readers done)
        if (l < NL - 1 && t < 368) *(us8*)d1 = vn;
    }
    __syncthreads();   // sY complete

    // ---- temporal FC: 92 p-tiles x 3 lp-tiles, K=32 MFMA + tail l=32..34 ----
    #pragma unroll 1
    for (int tt = w; tt < 276; tt += 8) {
        int pt = tt / 3, lt = tt - pt * 3;
        int pA = 16 * pt + lr;
        const unsigned short* yb = sY + pA * SYS + 8 * lg;
        union { bf16x8 v; unsigned u[4]; } au;
        au.u[0] = *(const unsigned*)(yb);
        au.u[1] = *(const unsigned*)(yb + 2);
        au.u[2] = *(const unsigned*)(yb + 4);
        au.u[3] = *(const unsigned*)(yb + 6);
        bf16x8 wbh = *(const bf16x8*)(sWTh + (16 * lt + lr) * 40 + 8 * lg);
        bf16x8 wbl = *(const bf16x8*)(sWTl + (16 * lt + lr) * 40 + 8 * lg);
        f32x4 c0 = __builtin_amdgcn_mfma_f32_16x16x32_bf16(au.v, wbh, zf, 0, 0, 0);
        f32x4 c1 = __builtin_amdgcn_mfma_f32_16x16x32_bf16(au.v, wbl, zf, 0, 0, 0);
        int lpc = 16 * lt + lr;
        if (lpc < 35) {
            float wt0 = sWt[lpc], wt1 = sWt[35 + lpc], wt2 = sWt[70 + lpc];
            float bv = sBias[lpc];
            #pragma unroll
            for (int r = 0; r < 4; r++) {
                int pr = 16 * pt + 4 * lg + r;
                const unsigned short* yt = sY + pr * SYS + 32;
                unsigned t0 = *(const unsigned*)(yt);       // l=32,33
                unsigned t1 = *(const unsigned*)(yt + 2);   // l=34, pad
                float v = c0[r] + c1[r] + bv
                        + bfh2f((unsigned short)(t0 & 0xffff)) * wt0
                        + bfh2f((unsigned short)(t0 >> 16))    * wt1
                        + bfh2f((unsigned short)(t1 & 0xffff)) * wt2;
                out[((size_t)b * 1472 + pr) * 35 + lpc] = v;
            }
        }
    }
}

// ---------------------------------------------------------------------------
extern "C" void kernel_launch(void* const* d_in, const int* in_sizes, int n_in,
                              void* d_out, int out_size, void* d_ws, size_t ws_size,
                              hipStream_t stream) {
    const float* x    = (const float*)d_in[0];
    const float* cw1  = (const float*)d_in[1];
    const float* cb1  = (const float*)d_in[2];
    const float* cw2  = (const float*)d_in[3];
    const float* cb2  = (const float*)d_in[4];
    const float* gam  = (const float*)d_in[5];
    const float* bet  = (const float*)d_in[6];
    const float* mw   = (const float*)d_in[7];
    const float* mb   = (const float*)d_in[8];
    const float* att  = (const float*)d_in[9];
    const float* aske = (const float*)d_in[10];
    const float* wsq  = (const float*)d_in[11];
    const float* bias = (const float*)d_in[12];
    float* ws = (float*)d_ws;
    float* out = (float*)d_out;

    hipLaunchKernelGGL(k_prep, dim3(4),       dim3(256),  0, stream, cw1, cb1, cw2, cb2, mw, mb, ws);
    hipLaunchKernelGGL(k_xt,   dim3(256, 4),  dim3(512),  0, stream, x, ws);
    hipLaunchKernelGGL(k_attm, dim3(256, 3),  dim3(256),  0, stream, ws);
    hipLaunchKernelGGL(k_bn,   dim3(25),      dim3(512),  0, stream, ws);
    hipLaunchKernelGGL(k_adp,  dim3(256, 3),  dim3(256),  0, stream, gam, bet, att, aske, ws);
    hipLaunchKernelGGL(k_fused, dim3(256),    dim3(512),  0, stream, ws, wsq, bias, out);
}

// Round 10
// 261.308 us; speedup vs baseline: 2.3105x; 1.0122x over previous
//
#include <hip/hip_runtime.h>
#include <hip/hip_bf16.h>

typedef __hip_bfloat16 bf16;
typedef __attribute__((ext_vector_type(8))) short bf16x8;
typedef __attribute__((ext_vector_type(4))) float f32x4;
typedef __attribute__((ext_vector_type(4))) unsigned short us4;
typedef __attribute__((ext_vector_type(8))) unsigned short us8;

// Problem constants
#define NB   256           // batch
#define NN   23            // nodes
#define NL   35            // seq len
#define NNL  805           // NN*NL
#define CNL  51520         // NC*NNL (per-batch x elements)
#define NSQ  529           // NN*NN
#define HF   1587          // NH*NSQ
#define NCN  1472          // 64*23 (one X_l slice)

// ws layout (float offsets)
#define OFF_W     0         // [3][64][64]
#define OFF_U1    12288
#define OFF_U2    12480
#define OFF_S     12672
#define OFF_ATTM  12800     // [256][1587]
#define OFF_MEAN  419072
#define OFF_RSTD  420672
#define OFF_A     422272    // [256][1587] -> 828544
#define OFF_MWH   828544    // mw bf16 hi [3][64o][64c] (12288 shorts)
#define OFF_MWL   834688    // mw bf16 lo
#define OFF_MBS   840832    // mbsum[64] -> pad 840960
#define OFF_XTB   840960    // X^T bf16 hi/lo [256][35][2 planes][23n][64c]

// split-bf16 helpers: x = hi + lo, each exactly representable in bf16
__device__ inline unsigned short bfh(float x) {
    unsigned u = __float_as_uint(x);
    return (unsigned short)((u + 0x7FFFu + ((u >> 16) & 1u)) >> 16);  // RNE
}
__device__ inline float bfh2f(unsigned short h) {
    return __uint_as_float(((unsigned)h) << 16);
}
// RNE f32->bf16 via HW cvt (numerically identical to bfh for finite inputs)
__device__ inline unsigned short bf16rn(float x) {
    __hip_bfloat16 h = __float2bfloat16(x);
    return __builtin_bit_cast(unsigned short, h);
}

// ---------------------------------------------------------------------------
// Kernel 0: transpose x[b][c][n][l] -> X^T bf16 hi/lo [b][l][p][n][c].
// Quarter-channel blocks: grid (256,4), 51.5 KB LDS -> 3 blocks/CU.
__global__ __launch_bounds__(512) void k_xt(const float* __restrict__ x,
                                            float* __restrict__ ws) {
    int b = blockIdx.x, ch = blockIdx.y, t = threadIdx.x;  // ch: 16-channel group
    __shared__ float sx[16 * 805];       // 51.5 KB
    const float* xb = x + b * CNL + ch * (16 * 805);
    unsigned short* xo = (unsigned short*)(ws + OFF_XTB) + (size_t)b * NL * 2944;
    for (int i = t; i < 16 * 805; i += 512) sx[i] = xb[i];
    __syncthreads();
    // item = (l, n, k2): k2 selects an 8-channel chunk; global c = 16ch + 8k2 + e
    for (int item = t; item < 35 * 46; item += 512) {
        int l = item / 46, rem = item - l * 46;
        int n = rem >> 1, k2 = rem & 1;
        us8 hi, lo;
        #pragma unroll
        for (int e = 0; e < 8; e++) {
            float v = sx[(8 * k2 + e) * 805 + n * 35 + l];
            unsigned short hb = bfh(v);
            hi[e] = hb;
            lo[e] = bfh(v - bfh2f(hb));
        }
        unsigned short* dst = xo + (size_t)l * 2944 + n * 64 + 8 * (2 * ch + k2);
        *(us8*)(dst) = hi;           // plane hi
        *(us8*)(dst + 1472) = lo;    // plane lo
    }
}

// ---------------------------------------------------------------------------
// Kernel 1: fold projection weights; block 3 converts mw to bf16 hi/lo + mb sum.
__global__ __launch_bounds__(256) void k_prep(const float* __restrict__ cw1,
                                              const float* __restrict__ cb1,
                                              const float* __restrict__ cw2,
                                              const float* __restrict__ cb2,
                                              const float* __restrict__ mw,
                                              const float* __restrict__ mb,
                                              float* __restrict__ ws) {
    int h = blockIdx.x, t = threadIdx.x;
    __shared__ float s1[4096], s2[4096];
    if (h < 3) {
        for (int i = t; i < 4096; i += 256) {
            s1[i] = cw1[h * 4096 + i];
            s2[i] = cw2[h * 4096 + i];
        }
        __syncthreads();
        for (int i = t; i < 4096; i += 256) {
            int c2 = i >> 6, c1 = i & 63;
            float acc = 0.f;
            for (int o = 0; o < 64; o++) acc += s2[o * 64 + c2] * s1[o * 64 + c1];
            ws[OFF_W + h * 4096 + i] = acc;
        }
        if (t < 64) {
            float a = 0.f, b2 = 0.f;
            for (int o = 0; o < 64; o++) {
                a  += cb2[h * 64 + o] * s1[o * 64 + t];
                b2 += cb1[h * 64 + o] * s2[o * 64 + t];
            }
            ws[OFF_U1 + h * 64 + t] = a;
            ws[OFF_U2 + h * 64 + t] = b2;
        }
        if (t == 0) {
            float a = 0.f;
            for (int o = 0; o < 64; o++) a += cb1[h * 64 + o] * cb2[h * 64 + o];
            ws[OFF_S + h] = a;
        }
    } else {
        unsigned short* mh = (unsigned short*)(ws + OFF_MWH);
        unsigned short* ml = (unsigned short*)(ws + OFF_MWL);
        for (int i = t; i < 12288; i += 256) {
            float v = mw[i];                 // layout [h][o][c]
            unsigned short hb = bfh(v);
            mh[i] = hb;
            ml[i] = bfh(v - bfh2f(hb));
        }
        if (t < 64) ws[OFF_MBS + t] = mb[t] + mb[64 + t] + mb[128 + t];
    }
}

// ---------------------------------------------------------------------------
// Kernel 2 (MFMA): att_m[b,h,m,n] = (sum_l X_l^T W X_l + a1[n] + a2[m] + 35*s)/2240
// 1-barrier pipeline: iteration l runs A(l+1) || B(l) in ONE barrier section.
// X triple-buffered (slots l%3), P double-buffered (l&1). Barriers 70 -> 37.
__global__ __launch_bounds__(256) void k_attm(float* __restrict__ ws) {
    const int b = blockIdx.x, h = blockIdx.y, t = threadIdx.x;
    const int lane = t & 63;
    const int w = __builtin_amdgcn_readfirstlane(t >> 6);   // wave 0..3
    const int lg = lane >> 4;      // k-group 0..3
    const int lr = lane & 15;      // row/col within 16-tile

    __shared__ unsigned short sXh[3][32 * 72];   // X^T hi, triple-buffered
    __shared__ unsigned short sXl[3][32 * 72];   // X^T lo
    __shared__ unsigned short sPh[2][32 * 72];   // P^T hi [n][c2], double-buffered
    __shared__ unsigned short sPl[2][32 * 72];   // P^T lo
    __shared__ float sxs[64 * 25];               // sum_l X  [c][n], stride 25
    __shared__ float sA1[23], sA2[23];

    const unsigned short* xthl = (const unsigned short*)(ws + OFF_XTB);

    // --- W fragments (phase-A A-operand), hoisted: rows 16w+lr, split hi/lo ---
    bf16x8 wh[2], wl[2];
    {
        const float* Wg = ws + OFF_W + h * 4096 + (16 * w + lr) * 64;
        #pragma unroll
        for (int s = 0; s < 2; s++) {
            const float* p = Wg + 32 * s + 8 * lg;
            float4 v0 = *(const float4*)(p);
            float4 v1 = *(const float4*)(p + 4);
            float vv[8] = {v0.x, v0.y, v0.z, v0.w, v1.x, v1.y, v1.z, v1.w};
            #pragma unroll
            for (int e = 0; e < 8; e++) {
                unsigned short hb = bfh(vv[e]);
                wh[s][e] = (short)hb;
                wl[s][e] = (short)bfh(vv[e] - bfh2f(hb));
            }
        }
    }

    // --- staging chunk decomposition (368 = 2 planes x 23 rows x 8 chunks) ---
    const int j1 = t;                              // chunk 1 (all threads)
    const int p1 = j1 / 184, r1 = j1 - p1 * 184;
    const int n1 = r1 >> 3, k1 = r1 & 7;
    unsigned short* d1 = (p1 ? sXl[0] : sXh[0]) + n1 * 72 + 8 * k1;
    const int j2 = 256 + t;                        // chunk 2 (t<112, plane lo)
    const int r2 = j2 - 184;
    const int n2 = r2 >> 3, k2 = r2 & 7;
    unsigned short* d2 = sXl[0] + n2 * 72 + 8 * k2;

    const int mt = w >> 1, nt = w & 1;             // phase-B tile
    f32x4 attC = {0.f, 0.f, 0.f, 0.f};
    float xa1[8] = {0, 0, 0, 0, 0, 0, 0, 0};
    float xa2[8] = {0, 0, 0, 0, 0, 0, 0, 0};

// phase A for slice LA: reads X slot LA%3, writes P buf LA&1
#define PHASE_A(LA)                                                            \
    {                                                                          \
        const int slA = (LA) % 3;                                              \
        const int pbA = (LA) & 1;                                              \
        const unsigned short* xhA = sXh[slA];                                  \
        const unsigned short* xlA = sXl[slA];                                  \
        f32x4 pcA[2];                                                          \
        _Pragma("unroll")                                                      \
        for (int ntt = 0; ntt < 2; ntt++) {                                    \
            f32x4 c = {0.f, 0.f, 0.f, 0.f};                                    \
            _Pragma("unroll")                                                  \
            for (int s = 0; s < 2; s++) {                                      \
                int off = (ntt * 16 + lr) * 72 + 32 * s + 8 * lg;              \
                bf16x8 bh = *(const bf16x8*)(xhA + off);                       \
                bf16x8 bl = *(const bf16x8*)(xlA + off);                       \
                c = __builtin_amdgcn_mfma_f32_16x16x32_bf16(wh[s], bh, c, 0, 0, 0); \
                c = __builtin_amdgcn_mfma_f32_16x16x32_bf16(wh[s], bl, c, 0, 0, 0); \
                c = __builtin_amdgcn_mfma_f32_16x16x32_bf16(wl[s], bh, c, 0, 0, 0); \
            }                                                                  \
            pcA[ntt] = c;                                                      \
        }                                                                      \
        _Pragma("unroll")                                                      \
        for (int ntt = 0; ntt < 2; ntt++) {                                    \
            int n = ntt * 16 + lr;                                             \
            int c2 = 16 * w + 4 * lg;                                          \
            us4 ph4, pl4;                                                      \
            _Pragma("unroll")                                                  \
            for (int r = 0; r < 4; r++) {                                      \
                float v = pcA[ntt][r];                                         \
                unsigned short hb = bf16rn(v);                                 \
                ph4[r] = hb;                                                   \
                pl4[r] = bf16rn(v - bfh2f(hb));                                \
            }                                                                  \
            *(us4*)(sPh[pbA] + n * 72 + c2) = ph4;                             \
            *(us4*)(sPl[pbA] + n * 72 + c2) = pl4;                             \
        }                                                                      \
    }

// phase B for slice L: reads X slot L%3 and P buf L&1, accumulates attC
#define PHASE_B(L)                                                             \
    {                                                                          \
        const int slB = (L) % 3;                                               \
        const int pbB = (L) & 1;                                               \
        const unsigned short* xhB = sXh[slB];                                  \
        const unsigned short* xlB = sXl[slB];                                  \
        _Pragma("unroll")                                                      \
        for (int s = 0; s < 2; s++) {                                          \
            int aoff = (mt * 16 + lr) * 72 + 32 * s + 8 * lg;                  \
            int boff = (nt * 16 + lr) * 72 + 32 * s + 8 * lg;                  \
            bf16x8 ah = *(const bf16x8*)(xhB + aoff);                          \
            bf16x8 al = *(const bf16x8*)(xlB + aoff);                          \
            bf16x8 bh = *(const bf16x8*)(sPh[pbB] + boff);                     \
            bf16x8 bl = *(const bf16x8*)(sPl[pbB] + boff);                     \
            attC = __builtin_amdgcn_mfma_f32_16x16x32_bf16(ah, bh, attC, 0, 0, 0); \
            attC = __builtin_amdgcn_mfma_f32_16x16x32_bf16(ah, bl, attC, 0, 0, 0); \
            attC = __builtin_amdgcn_mfma_f32_16x16x32_bf16(al, bh, attC, 0, 0, 0); \
        }                                                                      \
    }

    // --- prologue: stage l = 0,1 into slots 0,1; then A(0) fills P[0] ---
    #pragma unroll
    for (int l0 = 0; l0 < 2; l0++) {
        const us8* g = (const us8*)(xthl + (size_t)(b * NL + l0) * 2944);
        us8 v1 = g[j1];
        *(us8*)(d1 + l0 * 2304) = v1;
        #pragma unroll
        for (int e = 0; e < 8; e++) xa1[e] += bfh2f(v1[e]);
        if (t < 112) {
            us8 v2 = g[j2];
            *(us8*)(d2 + l0 * 2304) = v2;
            #pragma unroll
            for (int e = 0; e < 8; e++) xa2[e] += bfh2f(v2[e]);
        }
    }
    __syncthreads();   // slots 0,1 ready
    PHASE_A(0)         // P[0] ready after next barrier

    // --- main loop: ONE barrier per l; A(l+1) || B(l); stage X[l+2] late ---
    #pragma unroll 1
    for (int l = 0; l < NL; l++) {
        us8 vn1, vn2;
        if (l + 2 < NL) {
            const us8* g = (const us8*)(xthl + (size_t)(b * NL + l + 2) * 2944);
            vn1 = g[j1];
            if (t < 112) vn2 = g[j2];
        }
        __syncthreads();   // fences: A(l) P-write, X slot (l+1)%3 write
        __builtin_amdgcn_s_setprio(1);
        if (l + 1 < NL) PHASE_A(l + 1)
        PHASE_B(l)
        __builtin_amdgcn_s_setprio(0);
        if (l + 2 < NL) {
            int sl2o = ((l + 2) % 3) * 2304;
            *(us8*)(d1 + sl2o) = vn1;
            #pragma unroll
            for (int e = 0; e < 8; e++) xa1[e] += bfh2f(vn1[e]);
            if (t < 112) {
                *(us8*)(d2 + sl2o) = vn2;
                #pragma unroll
                for (int e = 0; e < 8; e++) xa2[e] += bfh2f(vn2[e]);
            }
        }
    }
#undef PHASE_A
#undef PHASE_B

    // --- rank-1 correction terms from hi+lo column sums ---
    if (t < 184) {
        #pragma unroll
        for (int e = 0; e < 8; e++) sxs[(8 * k1 + e) * 25 + n1] = xa1[e];
    }
    __syncthreads();
    if (t >= 184) {
        #pragma unroll
        for (int e = 0; e < 8; e++) sxs[(8 * k1 + e) * 25 + n1] += xa1[e];
    }
    if (t < 112) {
        #pragma unroll
        for (int e = 0; e < 8; e++) sxs[(8 * k2 + e) * 25 + n2] += xa2[e];
    }
    __syncthreads();
    if (t < 23) {
        float a = 0.f;
        const float* u = ws + OFF_U1 + h * 64;
        for (int c = 0; c < 64; c++) a += u[c] * sxs[c * 25 + t];
        sA1[t] = a;
    } else if (t >= 32 && t < 55) {
        int n = t - 32;
        float a = 0.f;
        const float* u = ws + OFF_U2 + h * 64;
        for (int c = 0; c < 64; c++) a += u[c] * sxs[c * 25 + n];
        sA2[n] = a;
    }
    __syncthreads();

    float sh = ws[OFF_S + h];
    float* o = ws + OFF_ATTM + (size_t)b * HF + h * NSQ;
    int n = nt * 16 + lr;
    if (n < 23) {
        #pragma unroll
        for (int r = 0; r < 4; r++) {
            int m = mt * 16 + 4 * lg + r;
            if (m < 23)
                o[m * 23 + n] = (attC[r] + sA1[n] + sA2[m] + 35.f * sh) * (1.f / 2240.f);
        }
    }
}

// ---------------------------------------------------------------------------
// Kernel 3: BN batch statistics; 25 blocks x (64 features x 8 batch-groups).
__global__ __launch_bounds__(512) void k_bn(float* __restrict__ ws) {
    int t = threadIdx.x;
    int fi = t & 63, bg = t >> 6;
    int f = blockIdx.x * 64 + fi;
    __shared__ float rs[8][64], rs2[8][64];
    float s = 0.f, s2 = 0.f;
    if (f < HF) {
        const float* p = ws + OFF_ATTM + f + (size_t)bg * 32 * HF;
        for (int b = 0; b < 32; b++) {
            float v = p[b * HF];
            s += v; s2 += v * v;
        }
    }
    rs[bg][fi] = s; rs2[bg][fi] = s2;
    __syncthreads();
    if (bg == 0 && f < HF) {
        float ts = 0.f, ts2 = 0.f;
        #pragma unroll
        for (int g = 0; g < 8; g++) { ts += rs[g][fi]; ts2 += rs2[g][fi]; }
        float mean = ts * (1.f / 256.f);
        float var  = ts2 * (1.f / 256.f) - mean * mean;
        ws[OFF_MEAN + f] = mean;
        ws[OFF_RSTD + f] = rsqrtf(var + 1e-5f);
    }
}

// ---------------------------------------------------------------------------
// Kernel 4: normalize, softmax over rows, A = A_ske + att + A_adp.
__global__ __launch_bounds__(256) void k_adp(const float* __restrict__ gamma,
                                             const float* __restrict__ beta,
                                             const float* __restrict__ att,
                                             const float* __restrict__ aske,
                                             float* __restrict__ ws) {
    int b = blockIdx.x, h = blockIdx.y, t = threadIdx.x;
    __shared__ float sv[529];
    const float* am   = ws + OFF_ATTM + b * HF + h * NSQ;
    const float* mean = ws + OFF_MEAN + h * NSQ;
    const float* rstd = ws + OFF_RSTD + h * NSQ;
    for (int i = t; i < 529; i += 256) {
        sv[i] = (am[i] - mean[i]) * rstd[i] * gamma[h * NSQ + i] + beta[h * NSQ + i];
    }
    __syncthreads();
    if (t < 23) {
        float mx = -1e30f;
        #pragma unroll
        for (int m = 0; m < 23; m++) mx = fmaxf(mx, sv[m * 23 + t]);
        float e[23];
        float sum = 0.f;
        #pragma unroll
        for (int m = 0; m < 23; m++) {
            float v = __expf(sv[m * 23 + t] - mx);
            e[m] = v; sum += v;
        }
        float inv = 1.f / sum;
        #pragma unroll
        for (int m = 0; m < 23; m++) sv[m * 23 + t] = e[m] * inv;
    }
    __syncthreads();
    float* o = ws + OFF_A + b * HF + h * NSQ;
    for (int i = t; i < 529; i += 256) {
        o[i] = sv[i] + aske[h * NSQ + i] + att[h * NSQ + i];
    }
}

// ---------------------------------------------------------------------------
// Kernel 5 (fused GCN + temporal FC), one block per batch b, 8 waves.
// Round-5 structure (sY LDS + post-loop MFMA FC) + T5 setprio on MFMA clusters.
#define SYS 38
#define STS 44
__global__ __launch_bounds__(512, 2) void k_fused(float* __restrict__ ws,
                                                  const float* __restrict__ wseq,
                                                  const float* __restrict__ biasp,
                                                  float* __restrict__ out) {
    const int b = blockIdx.x, t = threadIdx.x;
    const int lane = t & 63;
    const int w = __builtin_amdgcn_readfirstlane(t >> 6);   // 0..7
    const int lg = lane >> 4, lr = lane & 15;
    const int nt = w >> 2, ot = w & 3;     // phase A' tile (n-tile, o-tile)
    const int ot2 = w >> 1, mt = w & 1;    // phase B' tile (o-tile, m-tile)

    __shared__ __align__(16) unsigned short sXh[32 * 72], sXl[32 * 72];
    __shared__ __align__(16) unsigned short sAT[3][2][32 * 40];  // A^T [m][n] hi/lo
    __shared__ __align__(16) unsigned short sT[3][64 * STS];     // T [o][n] hi only
    __shared__ __align__(16) unsigned short sY[1472 * SYS];      // y bf16 [p][l]
    __shared__ __align__(16) unsigned short sWTh[48 * 40], sWTl[48 * 40]; // W^T [lp][l<32]
    __shared__ float sWt[3 * 35];        // W rows l=32..34
    __shared__ float sBias[35];

    const unsigned short* xthl = (const unsigned short*)(ws + OFF_XTB);
    const float* Ab  = ws + OFF_A + (size_t)b * HF;

    // ---- one-time: zero sX rows 23..31 (they feed phase B's K-dim via T) ----
    for (int i = t; i < 9 * 72; i += 512) {
        sXh[23 * 72 + i] = 0;
        sXl[23 * 72 + i] = 0;
    }
    // ---- one-time staging (first in-loop barrier fences all of it) ----
    for (int i = t; i < 3 * 1280; i += 512) {
        int h = i / 1280, r2 = i - h * 1280, m = r2 / 40, n = r2 - m * 40;
        float v = (n < 23 && m < 23) ? Ab[h * 529 + n * 23 + m] : 0.f;
        unsigned short hb = bfh(v);
        sAT[h][0][m * 40 + n] = hb;
        sAT[h][1][m * 40 + n] = bfh(v - bfh2f(hb));
    }
    for (int i = t; i < 48 * 40; i += 512) {
        int lp = i / 40, l = i - lp * 40;
        float v = (lp < 35 && l < 32) ? wseq[l * 35 + lp] : 0.f;
        unsigned short hb = bfh(v);
        sWTh[i] = hb;
        sWTl[i] = bfh(v - bfh2f(hb));
    }
    if (t < 105) sWt[t] = wseq[(32 + t / 35) * 35 + (t % 35)];
    if (t >= 128 && t < 163) sBias[t - 128] = biasp[t - 128];

    // ---- MW fragments as phase-A' B-operand (MW^T cols o = MW rows o) ----
    const unsigned short* mwh = (const unsigned short*)(ws + OFF_MWH);
    const unsigned short* mwl = (const unsigned short*)(ws + OFF_MWL);
    bf16x8 fwh[3][2], fwl[3][2];
    #pragma unroll
    for (int h = 0; h < 3; h++)
        #pragma unroll
        for (int s = 0; s < 2; s++) {
            int off = h * 4096 + (16 * ot + lr) * 64 + 32 * s + 8 * lg;
            fwh[h][s] = *(const bf16x8*)(mwh + off);
            fwl[h][s] = *(const bf16x8*)(mwl + off);
        }
    float4 mbsv = *(const float4*)(ws + OFF_MBS + 16 * ot2 + 4 * lg);
    float mb4[4] = {mbsv.x, mbsv.y, mbsv.z, mbsv.w};

    // staging chunk decomposition (t < 368 active)
    const int p1 = t / 184, r1 = t - p1 * 184;
    const int n1 = r1 >> 3, k1 = r1 & 7;
    unsigned short* d1 = (p1 ? sXl : sXh) + n1 * 72 + 8 * k1;

    const f32x4 zf = {0.f, 0.f, 0.f, 0.f};

    // prologue: stage l = 0
    if (t < 368) {
        const us8* g = (const us8*)(xthl + (size_t)(b * NL) * 2944);
        *(us8*)d1 = g[t];
    }

    #pragma unroll 1
    for (int l = 0; l < NL; l++) {
        __syncthreads();   // sX(l) ready

        // issue next-l load early (reg-carry; written after bar2)
        us8 vn;
        if (l < NL - 1 && t < 368) {
            const us8* g = (const us8*)(xthl + (size_t)(b * NL + l + 1) * 2944);
            vn = g[t];
        }

        // ---- phase A': T^T = X^T @ MW^T per h; M=n, N=o, K=c=64 ----
        bf16x8 xh0 = *(const bf16x8*)(sXh + (16 * nt + lr) * 72 + 8 * lg);
        bf16x8 xh1 = *(const bf16x8*)(sXh + (16 * nt + lr) * 72 + 32 + 8 * lg);
        bf16x8 xl0 = *(const bf16x8*)(sXl + (16 * nt + lr) * 72 + 8 * lg);
        bf16x8 xl1 = *(const bf16x8*)(sXl + (16 * nt + lr) * 72 + 32 + 8 * lg);
        __builtin_amdgcn_s_setprio(1);
        #pragma unroll
        for (int h = 0; h < 3; h++) {
            f32x4 cH = __builtin_amdgcn_mfma_f32_16x16x32_bf16(xh0, fwh[h][0], zf, 0, 0, 0);
            cH = __builtin_amdgcn_mfma_f32_16x16x32_bf16(xh1, fwh[h][1], cH, 0, 0, 0);
            f32x4 cC = __builtin_amdgcn_mfma_f32_16x16x32_bf16(xh0, fwl[h][0], zf, 0, 0, 0);
            cC = __builtin_amdgcn_mfma_f32_16x16x32_bf16(xh1, fwl[h][1], cC, 0, 0, 0);
            cC = __builtin_amdgcn_mfma_f32_16x16x32_bf16(xl0, fwh[h][0], cC, 0, 0, 0);
            cC = __builtin_amdgcn_mfma_f32_16x16x32_bf16(xl1, fwh[h][1], cC, 0, 0, 0);
            us4 t4;
            #pragma unroll
            for (int r = 0; r < 4; r++) t4[r] = bf16rn(cH[r] + cC[r]);
            *(us4*)(&sT[h][(16 * ot + lr) * STS + 16 * nt + 4 * lg]) = t4;
        }
        __builtin_amdgcn_s_setprio(0);
        __syncthreads();   // T ready; all phase-A' sX reads done

        // ---- phase B': Y(ot2,mt) = sum_h T[h] @ A[h]; K = n = 32 ----
        f32x4 Yh = zf, Yc = zf;
        __builtin_amdgcn_s_setprio(1);
        #pragma unroll
        for (int h = 0; h < 3; h++) {
            union { bf16x8 v; us4 q[2]; } tu;
            tu.q[0] = *(const us4*)(&sT[h][(16 * ot2 + lr) * STS + 8 * lg]);
            tu.q[1] = *(const us4*)(&sT[h][(16 * ot2 + lr) * STS + 8 * lg + 4]);
            bf16x8 ah = *(const bf16x8*)(&sAT[h][0][(16 * mt + lr) * 40 + 8 * lg]);
            bf16x8 al = *(const bf16x8*)(&sAT[h][1][(16 * mt + lr) * 40 + 8 * lg]);
            Yh = __builtin_amdgcn_mfma_f32_16x16x32_bf16(tu.v, ah, Yh, 0, 0, 0);
            Yc = __builtin_amdgcn_mfma_f32_16x16x32_bf16(tu.v, al, Yc, 0, 0, 0);
        }
        __builtin_amdgcn_s_setprio(0);
        int m = 16 * mt + lr;
        if (m < 23) {
            #pragma unroll
            for (int r = 0; r < 4; r++) {
                int o = 16 * ot2 + 4 * lg + r;
                float yv = Yh[r] + Yc[r] + mb4[r];
                sY[(o * 23 + m) * SYS + l] = bf16rn(yv);
            }
        }

        // write-late: store next-l X (safe: bar2 proved all A' readers done)
        if (l < NL - 1 && t < 368) *(us8*)d1 = vn;
    }
    __syncthreads();   // sY complete

    // ---- temporal FC: 92 p-tiles x 3 lp-tiles, K=32 MFMA + tail l=32..34 ----
    #pragma unroll 1
    for (int tt = w; tt < 276; tt += 8) {
        int pt = tt / 3, lt = tt - pt * 3;
        int pA = 16 * pt + lr;
        const unsigned short* yb = sY + pA * SYS + 8 * lg;
        union { bf16x8 v; unsigned u[4]; } au;
        au.u[0] = *(const unsigned*)(yb);
        au.u[1] = *(const unsigned*)(yb + 2);
        au.u[2] = *(const unsigned*)(yb + 4);
        au.u[3] = *(const unsigned*)(yb + 6);
        bf16x8 wbh = *(const bf16x8*)(sWTh + (16 * lt + lr) * 40 + 8 * lg);
        bf16x8 wbl = *(const bf16x8*)(sWTl + (16 * lt + lr) * 40 + 8 * lg);
        f32x4 c0 = __builtin_amdgcn_mfma_f32_16x16x32_bf16(au.v, wbh, zf, 0, 0, 0);
        f32x4 c1 = __builtin_amdgcn_mfma_f32_16x16x32_bf16(au.v, wbl, zf, 0, 0, 0);
        int lpc = 16 * lt + lr;
        if (lpc < 35) {
            float wt0 = sWt[lpc], wt1 = sWt[35 + lpc], wt2 = sWt[70 + lpc];
            float bv = sBias[lpc];
            #pragma unroll
            for (int r = 0; r < 4; r++) {
                int pr = 16 * pt + 4 * lg + r;
                const unsigned short* yt = sY + pr * SYS + 32;
                unsigned t0 = *(const unsigned*)(yt);       // l=32,33
                unsigned t1 = *(const unsigned*)(yt + 2);   // l=34, pad
                float v = c0[r] + c1[r] + bv
                        + bfh2f((unsigned short)(t0 & 0xffff)) * wt0
                        + bfh2f((unsigned short)(t0 >> 16))    * wt1
                        + bfh2f((unsigned short)(t1 & 0xffff)) * wt2;
                out[((size_t)b * 1472 + pr) * 35 + lpc] = v;
            }
        }
    }
}

// ---------------------------------------------------------------------------
extern "C" void kernel_launch(void* const* d_in, const int* in_sizes, int n_in,
                              void* d_out, int out_size, void* d_ws, size_t ws_size,
                              hipStream_t stream) {
    const float* x    = (const float*)d_in[0];
    const float* cw1  = (const float*)d_in[1];
    const float* cb1  = (const float*)d_in[2];
    const float* cw2  = (const float*)d_in[3];
    const float* cb2  = (const float*)d_in[4];
    const float* gam  = (const float*)d_in[5];
    const float* bet  = (const float*)d_in[6];
    const float* mw   = (const float*)d_in[7];
    const float* mb   = (const float*)d_in[8];
    const float* att  = (const float*)d_in[9];
    const float* aske = (const float*)d_in[10];
    const float* wsq  = (const float*)d_in[11];
    const float* bias = (const float*)d_in[12];
    float* ws = (float*)d_ws;
    float* out = (float*)d_out;

    hipLaunchKernelGGL(k_prep, dim3(4),       dim3(256),  0, stream, cw1, cb1, cw2, cb2, mw, mb, ws);
    hipLaunchKernelGGL(k_xt,   dim3(256, 4),  dim3(512),  0, stream, x, ws);
    hipLaunchKernelGGL(k_attm, dim3(256, 3),  dim3(256),  0, stream, ws);
    hipLaunchKernelGGL(k_bn,   dim3(25),      dim3(512),  0, stream, ws);
    hipLaunchKernelGGL(k_adp,  dim3(256, 3),  dim3(256),  0, stream, gam, bet, att, aske, ws);
    hipLaunchKernelGGL(k_fused, dim3(256),    dim3(512),  0, stream, ws, wsq, bias, out);
}